// Round 7
// baseline (168.360 us; speedup 1.0000x reference)
//
#include <hip/hip_runtime.h>

typedef unsigned short u16;
typedef unsigned int u32;

#define N_PTS 65536
#define KK 27
#define CIN 4
#define CC 32
#define NWIN 2048
#define CAP 32
#define NH 2
#define HD 16

typedef short s16x8 __attribute__((ext_vector_type(8)));
typedef float f32x4 __attribute__((ext_vector_type(4)));

__device__ __forceinline__ float bf2f(u16 h) { return __uint_as_float(((u32)h) << 16); }
__device__ __forceinline__ u16 f2bf(float f) {
    u32 u = __float_as_uint(f);
    u32 r = (u + 0x7FFFu + ((u >> 16) & 1u)) >> 16;
    return (u16)r;
}
__device__ __forceinline__ float ldany(const void* src, int i, bool isbf) {
    return isbf ? bf2f(((const u16*)src)[i]) : ((const float*)src)[i];
}
__device__ __forceinline__ u16 ldbf(const void* src, int i, bool isbf) {
    return isbf ? ((const u16*)src)[i] : f2bf(((const float*)src)[i]);
}

// ---- input float-dtype detection ----
__global__ void detect_kernel(const u32* __restrict__ w, int* flag) {
    int t = threadIdx.x;
    int cnt = 0;
    for (int i = t; i < 4096; i += 256) {
        u32 e = (w[i] >> 7) & 0xFFu;
        cnt += (e >= 100 && e <= 140) ? 1 : 0;
    }
    __shared__ int red[256];
    red[t] = cnt;
    __syncthreads();
    for (int s = 128; s > 0; s >>= 1) {
        if (t < s) red[t] += red[t + s];
        __syncthreads();
    }
    if (t == 0) flag[0] = (red[0] > 2048) ? 1 : 0;
}

// ---- single prep kernel ----
struct Ptrs { const void* p[24]; };

__global__ __launch_bounds__(256) void prep_all(
    Ptrs in, const int* __restrict__ flag,
    u16* __restrict__ fbf,
    u16* __restrict__ WpA1, u16* __restrict__ WpA2,
    u16* __restrict__ WpB1, u16* __restrict__ WpB2, u16* __restrict__ WpIN,
    u16* __restrict__ wqkvB, u16* __restrict__ wprojB,
    u16* __restrict__ tqB, u16* __restrict__ tkB, u16* __restrict__ tvB,
    float* __restrict__ Pf)
{
    bool isbf = flag[0] != 0;
    int seg = blockIdx.y;
    int i = blockIdx.x * 256 + threadIdx.x;
    if (seg == 0) {
        if (i < N_PTS * CIN) fbf[i] = ldbf(in.p[0], i, isbf);
        return;
    }
    if (seg <= 4) {
        if (i < 27648) {
            int e = i & 7, l = (i >> 3) & 63, dt = (i >> 9) & 1, k = i >> 10;
            const void* src = in.p[seg == 1 ? 7 : seg == 2 ? 10 : seg == 3 ? 13 : 16];
            u16* dst = seg == 1 ? WpA1 : seg == 2 ? WpA2 : seg == 3 ? WpB1 : WpB2;
            dst[i] = ldbf(src, k * 1024 + ((l >> 4) * 8 + e) * 32 + dt * 16 + (l & 15), isbf);
        }
        return;
    }
    if (seg == 5) {
        if (i < 4096) {
            int e = i & 7, l = (i >> 3) & 63, dt = (i >> 9) & 1, kk = i >> 10;
            int g = kk * 32 + (l >> 4) * 8 + e;
            int tp = g >> 2, c = g & 3;
            WpIN[i] = (tp < KK) ? ldbf(in.p[4], tp * 128 + c * 32 + dt * 16 + (l & 15), isbf) : (u16)0;
        }
        return;
    }
    if (seg == 6) {
        if (i < 3072) {
            int e = i & 7, l = (i >> 3) & 63, n = i >> 9;
            wqkvB[i] = ldbf(in.p[17], ((l >> 4) * 8 + e) * 96 + n * 16 + (l & 15), isbf);
        } else if (i < 4096) {
            int o2 = i - 3072;
            int e = o2 & 7, l = (o2 >> 3) & 63, n = o2 >> 9;
            wprojB[o2] = ldbf(in.p[19], ((l >> 4) * 8 + e) * 32 + n * 16 + (l & 15), isbf);
        }
        return;
    }
    if (seg == 7) {
        // rel tables in MFMA B-fragment order
        if (i < 9216) {
            int e = i & 7, l = (i >> 3) & 63, nn = i >> 9;
            int n = nn % 9, h = nn / 9, lr = l & 15, lg = l >> 4;
            int k = lg * 8 + e;
            tqB[i] = (k < HD) ? ldbf(in.p[21], (n * 16 + lr) * 32 + h * 16 + k, isbf) : (u16)0;
        } else if (i < 18432) {
            int o2 = i - 9216;
            int e = o2 & 7, l = (o2 >> 3) & 63, nn = o2 >> 9;
            int n = nn % 9, h = nn / 9, lr = l & 15, lg = l >> 4;
            int k = lg * 8 + e;
            tkB[o2] = (k < HD) ? ldbf(in.p[22], (n * 16 + lr) * 32 + h * 16 + k, isbf) : (u16)0;
        } else if (i < 23552) {
            int o2 = i - 18432;
            int e = o2 & 7, l = (o2 >> 3) & 63, kk2 = o2 >> 9;
            int ks = kk2 % 5, h = kk2 / 5, lr = l & 15, lg = l >> 4;
            int r = ks * 32 + lg * 8 + e;
            tvB[o2] = (r < 144) ? ldbf(in.p[23], r * 32 + h * 16 + lr, isbf) : (u16)0;
        }
        return;
    }
    // seg 8: small fp32 params: GB(8x32) | bqkv(96)@256 | bproj(32)@352
    if (i < 256) {
        const int srcs[8] = {5, 6, 8, 9, 11, 12, 14, 15};
        Pf[i] = ldany(in.p[srcs[i >> 5]], i & 31, isbf);
    } else if (i < 352) {
        Pf[i] = ldany(in.p[18], i - 256, isbf);
    } else if (i < 384) {
        Pf[i] = ldany(in.p[20], i - 352, isbf);
    }
}

// ---- split input conv: 4 waves share one 16-row tile (kk = wv) ----
__global__ __launch_bounds__(256) void convin_s(
    const u16* __restrict__ fb, const int* __restrict__ pairs,
    const u16* __restrict__ Wp, const float* __restrict__ gb,
    float* __restrict__ xbuf, u16* __restrict__ act_out)
{
    __shared__ float red[4][16][32];
    int t = threadIdx.x, wv = t >> 6, l = t & 63, lr = l & 15, lg = l >> 4;
    int p0 = blockIdx.x * 16;
    int rowaddr = p0 + lr;

    f32x4 acc0 = {0.f, 0.f, 0.f, 0.f}, acc1 = {0.f, 0.f, 0.f, 0.f};
    {
        int t0 = wv * 8 + lg * 2;
        int ta = t0 < 26 ? t0 : 26;
        int tb = (t0 + 1) < 26 ? (t0 + 1) : 26;
        int ia = pairs[ta * N_PTS + rowaddr];
        int ib = pairs[tb * N_PTS + rowaddr];
        u32 ma = (t0 < KK && ia >= 0) ? 0xFFFFFFFFu : 0u;
        u32 mb = (t0 + 1 < KK && ib >= 0) ? 0xFFFFFFFFu : 0u;
        uint2 qa = *(const uint2*)(fb + (long)(ia < 0 ? 0 : ia) * CIN);
        uint2 qb = *(const uint2*)(fb + (long)(ib < 0 ? 0 : ib) * CIN);
        union { uint4 q; s16x8 v; } a;
        a.q = make_uint4(qa.x & ma, qa.y & ma, qb.x & mb, qb.y & mb);
        const s16x8* wb = (const s16x8*)Wp + wv * 128 + l;
        s16x8 b0 = wb[0];
        s16x8 b1 = wb[64];
        acc0 = __builtin_amdgcn_mfma_f32_16x16x32_bf16(a.v, b0, acc0, 0, 0, 0);
        acc1 = __builtin_amdgcn_mfma_f32_16x16x32_bf16(a.v, b1, acc1, 0, 0, 0);
    }
#pragma unroll
    for (int r = 0; r < 4; r++) {
        red[wv][lg * 4 + r][lr] = acc0[r];
        red[wv][lg * 4 + r][lr + 16] = acc1[r];
    }
    __syncthreads();
#pragma unroll
    for (int e = t; e < 512; e += 256) {
        int row = e >> 5, c = e & 31;
        float v = red[0][row][c] + red[1][row][c] + red[2][row][c] + red[3][row][c];
        long o = (long)(p0 + row) * 32 + c;
        xbuf[o] = v;
        act_out[o] = f2bf(fmaxf(fmaf(v, gb[c], gb[32 + c]), 0.f));
    }
}

// ---- split 32->32 conv: 4 waves share one 16-row tile, 7 taps each ----
template <int M>
__global__ __launch_bounds__(256) void conv32s_mfma(
    const u16* __restrict__ act_in, const int* __restrict__ pairs,
    const u16* __restrict__ Wp, const float* __restrict__ gb,
    float* __restrict__ xbuf, u16* __restrict__ act_out)
{
    __shared__ float red[4][16][32];
    int t = threadIdx.x, wv = t >> 6, l = t & 63, lr = l & 15, lg = l >> 4;
    int p0 = blockIdx.x * 16;
    int rowaddr = p0 + lr;
    int k0 = wv * 7;

    int idx[7];
#pragma unroll
    for (int q = 0; q < 7; q++) {
        int k = k0 + q;
        idx[q] = (k < KK) ? pairs[k * N_PTS + rowaddr] : -1;
    }
    f32x4 acc0 = {0.f, 0.f, 0.f, 0.f}, acc1 = {0.f, 0.f, 0.f, 0.f};
#pragma unroll
    for (int q = 0; q < 7; q++) {
        int k = k0 + q;
        if (k >= KK) break;
        const s16x8* wb = (const s16x8*)Wp + k * 128 + l;
        s16x8 b0 = wb[0];
        s16x8 b1 = wb[64];
        int ic = idx[q] < 0 ? 0 : idx[q];
        uint4 qv = *(const uint4*)(act_in + (long)ic * CC + lg * 8);
        u32 msk = idx[q] >= 0 ? 0xFFFFFFFFu : 0u;
        qv.x &= msk; qv.y &= msk; qv.z &= msk; qv.w &= msk;
        union { uint4 q; s16x8 v; } a;
        a.q = qv;
        acc0 = __builtin_amdgcn_mfma_f32_16x16x32_bf16(a.v, b0, acc0, 0, 0, 0);
        acc1 = __builtin_amdgcn_mfma_f32_16x16x32_bf16(a.v, b1, acc1, 0, 0, 0);
    }
#pragma unroll
    for (int r = 0; r < 4; r++) {
        red[wv][lg * 4 + r][lr] = acc0[r];
        red[wv][lg * 4 + r][lr + 16] = acc1[r];
    }
    __syncthreads();
#pragma unroll
    for (int e = t; e < 512; e += 256) {
        int row = e >> 5, c = e & 31;
        float v = red[0][row][c] + red[1][row][c] + red[2][row][c] + red[3][row][c];
        long o = (long)(p0 + row) * 32 + c;
        if (M & 1) v += xbuf[o];
        if (M & 2) xbuf[o] = v;
        if (M & 4) act_out[o] = f2bf(fmaxf(fmaf(v, gb[c], gb[32 + c]), 0.f));
    }
}

// ---- attention v4: MFMA everywhere incl. rel-bias and tv ----
#define A_XW    0
#define A_RIDX  4224
#define A_QSB   8320
#define A_KSB   10880
#define A_VST   13440
#define A_SC    16000
#define A_OTB   26240
#define A_BIG   28800
#define A_WIDX  49280
#define A_SIZE  49408

__global__ __launch_bounds__(256) void attn4_kernel(
    const float* __restrict__ x, const int* __restrict__ win_idx,
    const int* __restrict__ rel_idx,
    const u16* __restrict__ wqkvB, const u16* __restrict__ wprojB,
    const float* __restrict__ Pf,
    const u16* __restrict__ tqB, const u16* __restrict__ tkB, const u16* __restrict__ tvB,
    float* __restrict__ out)
{
    __shared__ __align__(16) char arena[A_SIZE];
    float* xw   = (float*)(arena + A_XW);      // [32][33] f32
    int*   ridx = (int*)(arena + A_RIDX);      // [1024]
    u16*   qsb  = (u16*)(arena + A_QSB);       // [32][40] bf16
    u16*   ksb  = (u16*)(arena + A_KSB);
    u16*   vsT  = (u16*)(arena + A_VST);       // [d][tok]
    float* sc   = (float*)(arena + A_SC);      // [2][32][40] f32
    u16*   psb  = (u16*)(arena + A_SC);        // aliases sc after softmax
    u16*   otb  = (u16*)(arena + A_OTB);       // [32][40] bf16
    u16*   Bq   = (u16*)(arena + A_BIG);       // [32][160] bf16 (per h)
    u16*   Bk   = (u16*)(arena + A_BIG) + 5120;
    float* S    = (float*)(arena + A_BIG);     // [32][160] f32 (per h)
    u16*   Sb   = (u16*)(arena + A_BIG);       // bf16 in-place
    int*   widx = (int*)(arena + A_WIDX);

    int w = blockIdx.x, t = threadIdx.x;
    int wv = t >> 6, l = t & 63, lr = l & 15, lg = l >> 4;

    if (t < CAP) widx[t] = win_idx[w * CAP + t];
    __syncthreads();

    for (int e = t; e < CAP * CC; e += 256) {
        int i = e >> 5, c = e & 31;
        xw[i * 33 + c] = x[(long)widx[i] * CC + c];
        ridx[e] = rel_idx[(long)w * 1024 + e];
    }
    __syncthreads();

    // qkv: 12 MFMA
    {
        const float* bqkv = Pf + 256;
        for (int pi = wv; pi < 12; pi += 4) {
            int n = pi >> 1, m = pi & 1;
            union { s16x8 v; u16 h[8]; } a;
            const float* xr = xw + (m * 16 + lr) * 33;
#pragma unroll
            for (int e = 0; e < 8; e++) a.h[e] = f2bf(xr[lg * 8 + e]);
            s16x8 b = *(const s16x8*)(wqkvB + ((n * 64 + l) << 3));
            f32x4 acc = {0.f, 0.f, 0.f, 0.f};
            acc = __builtin_amdgcn_mfma_f32_16x16x32_bf16(a.v, b, acc, 0, 0, 0);
            int tt = n * 16 + lr;
            float bias = bqkv[tt];
#pragma unroll
            for (int r = 0; r < 4; r++) {
                int tok = m * 16 + lg * 4 + r;
                float v = acc[r] + bias;
                if (tt < 32)      qsb[tok * 40 + tt] = f2bf(v * 0.25f);   // HD^-0.5
                else if (tt < 64) ksb[tok * 40 + (tt - 32)] = f2bf(v);
                else              vsT[(tt - 64) * 40 + tok] = f2bf(v);
            }
        }
    }
    __syncthreads();

    // qk^T: 8 MFMA (K upper half zero)
    for (int pi = wv; pi < 8; pi += 4) {
        int h = pi >> 2, m = (pi >> 1) & 1, n = pi & 1;
        s16x8 a = {0, 0, 0, 0, 0, 0, 0, 0}, b = {0, 0, 0, 0, 0, 0, 0, 0};
        if (lg < 2) {
            a = *(const s16x8*)(qsb + (m * 16 + lr) * 40 + h * 16 + lg * 8);
            b = *(const s16x8*)(ksb + (n * 16 + lr) * 40 + h * 16 + lg * 8);
        }
        f32x4 acc = {0.f, 0.f, 0.f, 0.f};
        acc = __builtin_amdgcn_mfma_f32_16x16x32_bf16(a, b, acc, 0, 0, 0);
#pragma unroll
        for (int r = 0; r < 4; r++)
            sc[h * 1280 + (m * 16 + lg * 4 + r) * 40 + n * 16 + lr] = acc[r];
    }
    __syncthreads();

    // rel-bias: per h, Bq/Bk = q.tq^T / k.tk^T via 36 MFMA, then gather-add
    for (int h = 0; h < NH; h++) {
        for (int pi = wv; pi < 36; pi += 4) {
            int tb = pi >= 18 ? 1 : 0;
            int rem = pi - tb * 18;
            int m = rem / 9, n = rem % 9;
            const u16* src = tb ? ksb : qsb;
            const u16* tab = tb ? tkB : tqB;
            s16x8 a = {0, 0, 0, 0, 0, 0, 0, 0};
            if (lg < 2) a = *(const s16x8*)(src + (m * 16 + lr) * 40 + h * 16 + lg * 8);
            s16x8 b = *(const s16x8*)(tab + (((h * 9 + n) * 64 + l) << 3));
            f32x4 acc = {0.f, 0.f, 0.f, 0.f};
            acc = __builtin_amdgcn_mfma_f32_16x16x32_bf16(a, b, acc, 0, 0, 0);
            u16* dst = tb ? Bk : Bq;
#pragma unroll
            for (int r = 0; r < 4; r++)
                dst[(m * 16 + lg * 4 + r) * 160 + n * 16 + lr] = f2bf(acc[r]);
        }
        __syncthreads();
        for (int e = t; e < 1024; e += 256) {
            int i = e >> 5, j = e & 31, r = ridx[e];
            sc[h * 1280 + i * 40 + j] += bf2f(Bq[i * 160 + r]) + bf2f(Bk[j * 160 + r]);
        }
        __syncthreads();
    }

    // softmax (4 lanes/row) -> psb bf16 (aliases sc)
    {
        int rr = t >> 2, sub = t & 3;
        int h = rr >> 5, i = rr & 31, j0 = sub * 8;
        const float* srow = sc + h * 1280 + i * 40 + j0;
        float pv[8];
        float m_ = -1e30f;
#pragma unroll
        for (int jj = 0; jj < 8; jj++) { pv[jj] = srow[jj]; m_ = fmaxf(m_, pv[jj]); }
        m_ = fmaxf(m_, __shfl_xor(m_, 1));
        m_ = fmaxf(m_, __shfl_xor(m_, 2));
        float sum = 0.f;
#pragma unroll
        for (int jj = 0; jj < 8; jj++) { pv[jj] = __expf(pv[jj] - m_); sum += pv[jj]; }
        sum += __shfl_xor(sum, 1);
        sum += __shfl_xor(sum, 2);
        float inv = 1.f / sum;
        __syncthreads();   // all sc reads complete before psb overwrite
        u16* prow = psb + h * 1280 + i * 40 + j0;
#pragma unroll
        for (int jj = 0; jj < 8; jj++) prow[jj] = f2bf(pv[jj] * inv);
    }
    __syncthreads();

    // per h: S scatter -> bf16 -> chained PV+tv MFMA
    for (int h = 0; h < NH; h++) {
        for (int e = t; e < 5120; e += 256) S[e] = 0.f;
        __syncthreads();
        for (int e = t; e < 1024; e += 256) {
            int i = e >> 5, j = e & 31, r = ridx[e];
            float p = bf2f(psb[h * 1280 + i * 40 + j]);
            atomicAdd(&S[i * 160 + r], p);
        }
        __syncthreads();
        float tmp[20];
#pragma unroll
        for (int q = 0; q < 20; q++) tmp[q] = S[t + q * 256];
        __syncthreads();
#pragma unroll
        for (int q = 0; q < 20; q++) Sb[t + q * 256] = f2bf(tmp[q]);
        __syncthreads();
        if ((wv >> 1) == h) {
            int m = wv & 1;
            f32x4 acc = {0.f, 0.f, 0.f, 0.f};
            s16x8 a = *(const s16x8*)(psb + h * 1280 + (m * 16 + lr) * 40 + lg * 8);
            s16x8 b = *(const s16x8*)(vsT + (h * 16 + lr) * 40 + lg * 8);
            acc = __builtin_amdgcn_mfma_f32_16x16x32_bf16(a, b, acc, 0, 0, 0);
#pragma unroll
            for (int ks = 0; ks < 5; ks++) {
                s16x8 a2 = *(const s16x8*)(Sb + (m * 16 + lr) * 160 + ks * 32 + lg * 8);
                s16x8 b2 = *(const s16x8*)(tvB + (((h * 5 + ks) * 64 + l) << 3));
                acc = __builtin_amdgcn_mfma_f32_16x16x32_bf16(a2, b2, acc, 0, 0, 0);
            }
#pragma unroll
            for (int r = 0; r < 4; r++)
                otb[(m * 16 + lg * 4 + r) * 40 + h * 16 + lr] = f2bf(acc[r]);
        }
        __syncthreads();
    }

    // proj: 4 MFMA + residual scatter
    {
        int m = wv >> 1, n = wv & 1;
        s16x8 a = *(const s16x8*)(otb + (m * 16 + lr) * 40 + lg * 8);
        s16x8 b = *(const s16x8*)(wprojB + ((n * 64 + l) << 3));
        f32x4 acc = {0.f, 0.f, 0.f, 0.f};
        acc = __builtin_amdgcn_mfma_f32_16x16x32_bf16(a, b, acc, 0, 0, 0);
        int c = n * 16 + lr;
        float bb = Pf[352 + c];
#pragma unroll
        for (int r = 0; r < 4; r++) {
            int tok = m * 16 + lg * 4 + r;
            out[(long)widx[tok] * CC + c] = xw[tok * 33 + c] + bb + acc[r];
        }
    }
}

// ---- ws byte offsets ----
#define B_PF     0
#define B_FLAG   1536
#define B_ACTA   2048
#define B_ACTB   4196352
#define B_FEATS  8390656
#define B_WA1    8914944
#define B_WA2    8970240
#define B_WB1    9025536
#define B_WB2    9080832
#define B_WIN    9136128
#define B_WQKVB  9144320
#define B_WPROJB 9150464
#define B_TQBF   9152512
#define B_TKBF   9170944
#define B_TVBF   9189376

extern "C" void kernel_launch(void* const* d_in, const int* in_sizes, int n_in,
                              void* d_out, int out_size, void* d_ws, size_t ws_size,
                              hipStream_t stream) {
    const void* feats  = d_in[0];
    const int* pairs   = (const int*)d_in[1];
    const int* win_idx = (const int*)d_in[2];
    const int* rel_idx = (const int*)d_in[3];

    char* wsb = (char*)d_ws;
    float* Pf = (float*)(wsb + B_PF);
    int* flag = (int*)(wsb + B_FLAG);
    u16* actA = (u16*)(wsb + B_ACTA);
    u16* actB = (u16*)(wsb + B_ACTB);
    u16* fbf  = (u16*)(wsb + B_FEATS);
    u16* WpA1 = (u16*)(wsb + B_WA1);
    u16* WpA2 = (u16*)(wsb + B_WA2);
    u16* WpB1 = (u16*)(wsb + B_WB1);
    u16* WpB2 = (u16*)(wsb + B_WB2);
    u16* WpIN = (u16*)(wsb + B_WIN);
    u16* wqkvB  = (u16*)(wsb + B_WQKVB);
    u16* wprojB = (u16*)(wsb + B_WPROJB);
    u16* tqB = (u16*)(wsb + B_TQBF);
    u16* tkB = (u16*)(wsb + B_TKBF);
    u16* tvB = (u16*)(wsb + B_TVBF);
    float* X  = (float*)d_out;

    detect_kernel<<<1, 256, 0, stream>>>((const u32*)feats, flag);

    Ptrs pp;
    for (int i = 0; i < 24; i++) pp.p[i] = d_in[i];
    prep_all<<<dim3(1024, 9), 256, 0, stream>>>(pp, flag, fbf,
                                                WpA1, WpA2, WpB1, WpB2, WpIN,
                                                wqkvB, wprojB, tqB, tkB, tvB, Pf);

    convin_s<<<4096, 256, 0, stream>>>(fbf, pairs, WpIN, Pf + 0, X, actA);
    conv32s_mfma<4><<<4096, 256, 0, stream>>>(actA, pairs, WpA1, Pf + 64,  X, actB);
    conv32s_mfma<7><<<4096, 256, 0, stream>>>(actB, pairs, WpA2, Pf + 128, X, actA);
    conv32s_mfma<4><<<4096, 256, 0, stream>>>(actA, pairs, WpB1, Pf + 192, X, actB);
    conv32s_mfma<3><<<4096, 256, 0, stream>>>(actB, pairs, WpB2, Pf, X, actA);

    attn4_kernel<<<NWIN, 256, 0, stream>>>(X, win_idx, rel_idx,
                                           wqkvB, wprojB, Pf,
                                           tqB, tkB, tvB, X);
}

// Round 8
// 135.211 us; speedup vs baseline: 1.2452x; 1.2452x over previous
//
#include <hip/hip_runtime.h>

typedef unsigned short u16;
typedef unsigned int u32;

#define N_PTS 65536
#define KK 27
#define CIN 4
#define CC 32
#define NWIN 2048
#define CAP 32
#define NH 2
#define HD 16

typedef short s16x8 __attribute__((ext_vector_type(8)));
typedef float f32x4 __attribute__((ext_vector_type(4)));

__device__ __forceinline__ float bf2f(u16 h) { return __uint_as_float(((u32)h) << 16); }
__device__ __forceinline__ u16 f2bf(float f) {
    u32 u = __float_as_uint(f);
    u32 r = (u + 0x7FFFu + ((u >> 16) & 1u)) >> 16;
    return (u16)r;
}
__device__ __forceinline__ float ldany(const void* src, int i, bool isbf) {
    return isbf ? bf2f(((const u16*)src)[i]) : ((const float*)src)[i];
}
__device__ __forceinline__ u16 ldbf(const void* src, int i, bool isbf) {
    return isbf ? ((const u16*)src)[i] : f2bf(((const float*)src)[i]);
}

// ---- input float-dtype detection ----
__global__ void detect_kernel(const u32* __restrict__ w, int* flag) {
    int t = threadIdx.x;
    int cnt = 0;
    for (int i = t; i < 4096; i += 256) {
        u32 e = (w[i] >> 7) & 0xFFu;
        cnt += (e >= 100 && e <= 140) ? 1 : 0;
    }
    __shared__ int red[256];
    red[t] = cnt;
    __syncthreads();
    for (int s = 128; s > 0; s >>= 1) {
        if (t < s) red[t] += red[t + s];
        __syncthreads();
    }
    if (t == 0) flag[0] = (red[0] > 2048) ? 1 : 0;
}

// ---- single prep kernel ----
struct Ptrs { const void* p[24]; };

__global__ __launch_bounds__(256) void prep_all(
    Ptrs in, const int* __restrict__ flag,
    u16* __restrict__ fbf,
    u16* __restrict__ WpA1, u16* __restrict__ WpA2,
    u16* __restrict__ WpB1, u16* __restrict__ WpB2, u16* __restrict__ WpIN,
    u16* __restrict__ wqkvB, u16* __restrict__ wprojB,
    u16* __restrict__ tqB, u16* __restrict__ tkB, u16* __restrict__ tvb,
    float* __restrict__ Pf)
{
    bool isbf = flag[0] != 0;
    int seg = blockIdx.y;
    int i = blockIdx.x * 256 + threadIdx.x;
    if (seg == 0) {
        if (i < N_PTS * CIN) fbf[i] = ldbf(in.p[0], i, isbf);
        return;
    }
    if (seg <= 4) {
        if (i < 27648) {
            int e = i & 7, l = (i >> 3) & 63, dt = (i >> 9) & 1, k = i >> 10;
            const void* src = in.p[seg == 1 ? 7 : seg == 2 ? 10 : seg == 3 ? 13 : 16];
            u16* dst = seg == 1 ? WpA1 : seg == 2 ? WpA2 : seg == 3 ? WpB1 : WpB2;
            dst[i] = ldbf(src, k * 1024 + ((l >> 4) * 8 + e) * 32 + dt * 16 + (l & 15), isbf);
        }
        return;
    }
    if (seg == 5) {
        if (i < 4096) {
            int e = i & 7, l = (i >> 3) & 63, dt = (i >> 9) & 1, kk = i >> 10;
            int g = kk * 32 + (l >> 4) * 8 + e;
            int tp = g >> 2, c = g & 3;
            WpIN[i] = (tp < KK) ? ldbf(in.p[4], tp * 128 + c * 32 + dt * 16 + (l & 15), isbf) : (u16)0;
        }
        return;
    }
    if (seg == 6) {
        if (i < 3072) {
            int e = i & 7, l = (i >> 3) & 63, n = i >> 9;
            wqkvB[i] = ldbf(in.p[17], ((l >> 4) * 8 + e) * 96 + n * 16 + (l & 15), isbf);
        } else if (i < 4096) {
            int o2 = i - 3072;
            int e = o2 & 7, l = (o2 >> 3) & 63, n = o2 >> 9;
            wprojB[o2] = ldbf(in.p[19], ((l >> 4) * 8 + e) * 32 + n * 16 + (l & 15), isbf);
        }
        return;
    }
    if (seg == 7) {
        // tq/tk in MFMA B-fragment order; tv plain [144][32]
        if (i < 9216) {
            int e = i & 7, l = (i >> 3) & 63, nn = i >> 9;
            int n = nn % 9, h = nn / 9, lr = l & 15, lg = l >> 4;
            int k = lg * 8 + e;
            tqB[i] = (k < HD) ? ldbf(in.p[21], (n * 16 + lr) * 32 + h * 16 + k, isbf) : (u16)0;
        } else if (i < 18432) {
            int o2 = i - 9216;
            int e = o2 & 7, l = (o2 >> 3) & 63, nn = o2 >> 9;
            int n = nn % 9, h = nn / 9, lr = l & 15, lg = l >> 4;
            int k = lg * 8 + e;
            tkB[o2] = (k < HD) ? ldbf(in.p[22], (n * 16 + lr) * 32 + h * 16 + k, isbf) : (u16)0;
        } else if (i < 23040) {
            int o2 = i - 18432;
            tvb[o2] = ldbf(in.p[23], o2, isbf);
        }
        return;
    }
    // seg 8: GB(8x32) | bqkv(96)@256 | bproj(32)@352
    if (i < 256) {
        const int srcs[8] = {5, 6, 8, 9, 11, 12, 14, 15};
        Pf[i] = ldany(in.p[srcs[i >> 5]], i & 31, isbf);
    } else if (i < 352) {
        Pf[i] = ldany(in.p[18], i - 256, isbf);
    } else if (i < 384) {
        Pf[i] = ldany(in.p[20], i - 352, isbf);
    }
}

// ---- MFMA input conv (round-6 version) ----
__global__ __launch_bounds__(256) void convin_mfma(
    const u16* __restrict__ fb, const int* __restrict__ pairs,
    const u16* __restrict__ Wp, const float* __restrict__ gb,
    float* __restrict__ xbuf, u16* __restrict__ act_out)
{
    int t = threadIdx.x;
    int wv = t >> 6, l = t & 63;
    int lr = l & 15, lg = l >> 4;
    int p0 = (blockIdx.x * 4 + wv) * 16;
    int rowaddr = p0 + lr;

    f32x4 acc0 = {0.f, 0.f, 0.f, 0.f}, acc1 = {0.f, 0.f, 0.f, 0.f};
#pragma unroll
    for (int kk = 0; kk < 4; kk++) {
        int t0 = kk * 8 + lg * 2;
        int ta = t0 < 26 ? t0 : 26;
        int tb = (t0 + 1) < 26 ? (t0 + 1) : 26;
        int ia = pairs[ta * N_PTS + rowaddr];
        int ib = pairs[tb * N_PTS + rowaddr];
        u32 ma = (t0 < KK && ia >= 0) ? 0xFFFFFFFFu : 0u;
        u32 mb = (t0 + 1 < KK && ib >= 0) ? 0xFFFFFFFFu : 0u;
        uint2 qa = *(const uint2*)(fb + (long)(ia < 0 ? 0 : ia) * CIN);
        uint2 qb = *(const uint2*)(fb + (long)(ib < 0 ? 0 : ib) * CIN);
        union { uint4 q; s16x8 v; } a;
        a.q = make_uint4(qa.x & ma, qa.y & ma, qb.x & mb, qb.y & mb);
        const s16x8* wb = (const s16x8*)Wp + kk * 128 + l;
        s16x8 b0 = wb[0];
        s16x8 b1 = wb[64];
        acc0 = __builtin_amdgcn_mfma_f32_16x16x32_bf16(a.v, b0, acc0, 0, 0, 0);
        acc1 = __builtin_amdgcn_mfma_f32_16x16x32_bf16(a.v, b1, acc1, 0, 0, 0);
    }
    float g0 = gb[lr], b0v = gb[32 + lr], g1 = gb[16 + lr], b1v = gb[48 + lr];
#pragma unroll
    for (int r = 0; r < 4; r++) {
        int row = p0 + lg * 4 + r;
        long o0 = (long)row * 32 + lr, o1 = o0 + 16;
        float v0 = acc0[r], v1 = acc1[r];
        xbuf[o0] = v0; xbuf[o1] = v1;
        act_out[o0] = f2bf(fmaxf(fmaf(v0, g0, b0v), 0.f));
        act_out[o1] = f2bf(fmaxf(fmaf(v1, g1, b1v), 0.f));
    }
}

// ---- MFMA 32->32 gather conv; 8-deep explicit gather prefetch ----
// M: bit0 READ_X, bit1 WRITE_X, bit2 WRITE_ACT
template <int M>
__global__ __launch_bounds__(256) void conv32_mfma(
    const u16* __restrict__ act_in, const int* __restrict__ pairs,
    const u16* __restrict__ Wp, const float* __restrict__ gb,
    float* __restrict__ xbuf, u16* __restrict__ act_out)
{
    int t = threadIdx.x;
    int wv = t >> 6, l = t & 63;
    int lr = l & 15, lg = l >> 4;
    int p0 = (blockIdx.x * 4 + wv) * 16;
    int rowaddr = p0 + lr;

    int idx[KK];
#pragma unroll
    for (int k = 0; k < KK; k++) idx[k] = pairs[k * N_PTS + rowaddr];

    uint4 qb[8];
#pragma unroll
    for (int k = 0; k < 8; k++) {
        int ic = idx[k] < 0 ? 0 : idx[k];
        qb[k] = *(const uint4*)(act_in + (long)ic * CC + lg * 8);
    }

    f32x4 acc0 = {0.f, 0.f, 0.f, 0.f}, acc1 = {0.f, 0.f, 0.f, 0.f};
#pragma unroll
    for (int k = 0; k < KK; k++) {
        uint4 q = qb[k & 7];
        if (k + 8 < KK) {
            int kn = k + 8;
            int ic = idx[kn] < 0 ? 0 : idx[kn];
            qb[kn & 7] = *(const uint4*)(act_in + (long)ic * CC + lg * 8);
        }
        u32 msk = idx[k] >= 0 ? 0xFFFFFFFFu : 0u;
        q.x &= msk; q.y &= msk; q.z &= msk; q.w &= msk;
        union { uint4 q; s16x8 v; } a;
        a.q = q;
        const s16x8* wb = (const s16x8*)Wp + k * 128 + l;
        s16x8 b0 = wb[0];
        s16x8 b1 = wb[64];
        acc0 = __builtin_amdgcn_mfma_f32_16x16x32_bf16(a.v, b0, acc0, 0, 0, 0);
        acc1 = __builtin_amdgcn_mfma_f32_16x16x32_bf16(a.v, b1, acc1, 0, 0, 0);
    }
    float g0 = 0.f, b0v = 0.f, g1 = 0.f, b1v = 0.f;
    if (M & 4) { g0 = gb[lr]; b0v = gb[32 + lr]; g1 = gb[16 + lr]; b1v = gb[48 + lr]; }
#pragma unroll
    for (int r = 0; r < 4; r++) {
        int row = p0 + lg * 4 + r;
        long o0 = (long)row * 32 + lr, o1 = o0 + 16;
        float v0 = acc0[r], v1 = acc1[r];
        if (M & 1) { v0 += xbuf[o0]; v1 += xbuf[o1]; }
        if (M & 2) { xbuf[o0] = v0; xbuf[o1] = v1; }
        if (M & 4) {
            act_out[o0] = f2bf(fmaxf(fmaf(v0, g0, b0v), 0.f));
            act_out[o1] = f2bf(fmaxf(fmaf(v1, g1, b1v), 0.f));
        }
    }
}

// ---- attention v5: attn3 structure + per-h MFMA rel-bias, 38.5KB LDS ----
#define A5_RIDX 0
#define A5_QSB  4096
#define A5_KSB  6656
#define A5_VST  9216
#define A5_SC   11776     // [2][32][36] f32 (psb bf16 [2][32][40] aliases base)
#define A5_BQ   20992     // [32][144] bf16  (ot f32 [32][36] aliases base later)
#define A5_BK   30208     // [32][144] bf16
#define A5_SIZE 39424

__global__ __launch_bounds__(256) void attn5_kernel(
    const float* __restrict__ x, const int* __restrict__ win_idx,
    const int* __restrict__ rel_idx,
    const u16* __restrict__ wqkvB, const u16* __restrict__ wprojB,
    const float* __restrict__ Pf,
    const u16* __restrict__ tqB, const u16* __restrict__ tkB, const u16* __restrict__ tvb,
    float* __restrict__ out)
{
    __shared__ __align__(16) char arena[A5_SIZE];
    int*   ridx = (int*)(arena + A5_RIDX);
    u16*   qsb  = (u16*)(arena + A5_QSB);
    u16*   ksb  = (u16*)(arena + A5_KSB);
    u16*   vsT  = (u16*)(arena + A5_VST);
    float* sc   = (float*)(arena + A5_SC);
    u16*   psb  = (u16*)(arena + A5_SC);
    u16*   Bq   = (u16*)(arena + A5_BQ);
    u16*   Bk   = (u16*)(arena + A5_BK);
    float* ot   = (float*)(arena + A5_BQ);

    int w = blockIdx.x, t = threadIdx.x;
    int wv = t >> 6, l = t & 63, lr = l & 15, lg = l >> 4;

    // ridx (vector) + qkv MFMA
    {
        int4 r4 = *(const int4*)(rel_idx + (long)w * 1024 + t * 4);
        *(int4*)(ridx + t * 4) = r4;
    }
    {
        const float* bqkv = Pf + 256;
        for (int pi = wv; pi < 12; pi += 4) {
            int n = pi >> 1, m = pi & 1;
            int gi = win_idx[w * 32 + m * 16 + lr];
            const float* xr = x + (long)gi * 32 + lg * 8;
            float4 x0 = *(const float4*)(xr);
            float4 x1 = *(const float4*)(xr + 4);
            union { s16x8 v; u16 h[8]; } a;
            a.h[0] = f2bf(x0.x); a.h[1] = f2bf(x0.y); a.h[2] = f2bf(x0.z); a.h[3] = f2bf(x0.w);
            a.h[4] = f2bf(x1.x); a.h[5] = f2bf(x1.y); a.h[6] = f2bf(x1.z); a.h[7] = f2bf(x1.w);
            s16x8 b = *(const s16x8*)(wqkvB + ((n * 64 + l) << 3));
            f32x4 acc = {0.f, 0.f, 0.f, 0.f};
            acc = __builtin_amdgcn_mfma_f32_16x16x32_bf16(a.v, b, acc, 0, 0, 0);
            int tt = n * 16 + lr;
            float bias = bqkv[tt];
#pragma unroll
            for (int r = 0; r < 4; r++) {
                int tok = m * 16 + lg * 4 + r;
                float v = acc[r] + bias;
                if (tt < 32)      qsb[tok * 40 + tt] = f2bf(v * 0.25f);   // HD^-0.5
                else if (tt < 64) ksb[tok * 40 + (tt - 32)] = f2bf(v);
                else              vsT[(tt - 64) * 40 + tok] = f2bf(v);
            }
        }
    }
    __syncthreads();

    // per-h: Bq/Bk MFMA then bias-init of sc
    for (int h = 0; h < NH; h++) {
        for (int pi = wv; pi < 36; pi += 4) {
            int tb = pi >= 18 ? 1 : 0;
            int rem = pi - tb * 18;
            int m = rem / 9, n = rem % 9;
            const u16* src = tb ? ksb : qsb;
            const u16* tab = tb ? tkB : tqB;
            s16x8 a = {0, 0, 0, 0, 0, 0, 0, 0};
            if (lg < 2) a = *(const s16x8*)(src + (m * 16 + lr) * 40 + h * 16 + lg * 8);
            s16x8 b = *(const s16x8*)(tab + (((h * 9 + n) * 64 + l) << 3));
            f32x4 acc = {0.f, 0.f, 0.f, 0.f};
            acc = __builtin_amdgcn_mfma_f32_16x16x32_bf16(a, b, acc, 0, 0, 0);
            u16* dst = tb ? Bk : Bq;
#pragma unroll
            for (int r = 0; r < 4; r++)
                dst[(m * 16 + lg * 4 + r) * 144 + n * 16 + lr] = f2bf(acc[r]);
        }
        __syncthreads();
        for (int e = t; e < 1024; e += 256) {
            int i = e >> 5, j = e & 31, r = ridx[e];
            sc[h * 1152 + i * 36 + j] = bf2f(Bq[i * 144 + r]) + bf2f(Bk[j * 144 + r]);
        }
        __syncthreads();
    }

    // qk^T: 8 MFMA added into sc (owner-lane RMW)
    for (int pi = wv; pi < 8; pi += 4) {
        int h = pi >> 2, m = (pi >> 1) & 1, n = pi & 1;
        s16x8 a = {0, 0, 0, 0, 0, 0, 0, 0}, b = {0, 0, 0, 0, 0, 0, 0, 0};
        if (lg < 2) {
            a = *(const s16x8*)(qsb + (m * 16 + lr) * 40 + h * 16 + lg * 8);
            b = *(const s16x8*)(ksb + (n * 16 + lr) * 40 + h * 16 + lg * 8);
        }
        f32x4 acc = {0.f, 0.f, 0.f, 0.f};
        acc = __builtin_amdgcn_mfma_f32_16x16x32_bf16(a, b, acc, 0, 0, 0);
#pragma unroll
        for (int r = 0; r < 4; r++)
            sc[h * 1152 + (m * 16 + lg * 4 + r) * 36 + n * 16 + lr] += acc[r];
    }
    __syncthreads();

    // softmax (4 lanes/row) -> psb bf16 (aliases sc base)
    {
        int rr = t >> 2, sub = t & 3;
        int h = rr >> 5, i = rr & 31, j0 = sub * 8;
        const float* srow = sc + h * 1152 + i * 36 + j0;
        float pv[8];
        float m_ = -1e30f;
#pragma unroll
        for (int jj = 0; jj < 8; jj++) { pv[jj] = srow[jj]; m_ = fmaxf(m_, pv[jj]); }
        m_ = fmaxf(m_, __shfl_xor(m_, 1));
        m_ = fmaxf(m_, __shfl_xor(m_, 2));
        float sum = 0.f;
#pragma unroll
        for (int jj = 0; jj < 8; jj++) { pv[jj] = __expf(pv[jj] - m_); sum += pv[jj]; }
        sum += __shfl_xor(sum, 1);
        sum += __shfl_xor(sum, 2);
        float inv = 1.f / sum;
        __syncthreads();   // all sc reads complete before alias overwrite
        u16* prow = psb + h * 1280 + i * 40 + j0;
#pragma unroll
        for (int jj = 0; jj < 8; jj++) prow[jj] = f2bf(pv[jj] * inv);
    }
    __syncthreads();

    // tv gather: ot init (Bq/Bk region now dead)
    for (int o = t; o < CAP * 16; o += 256) {
        int i = o >> 4, hp = o & 15, h = hp >> 3;
        const u16* prow = psb + h * 1280 + i * 40;
        const int* rrow = ridx + i * 32;
        float a0 = 0.f, a1 = 0.f;
#pragma unroll 8
        for (int j = 0; j < CAP; j++) {
            int r = rrow[j];
            float p = bf2f(prow[j]);
            u32 tv2 = *(const u32*)(tvb + r * 32 + hp * 2);
            a0 = fmaf(p, __uint_as_float(tv2 << 16), a0);
            a1 = fmaf(p, __uint_as_float(tv2 & 0xffff0000u), a1);
        }
        ot[i * 36 + hp * 2] = a0;
        ot[i * 36 + hp * 2 + 1] = a1;
    }
    __syncthreads();

    // PV: 4 MFMA, added into ot (owner-lane RMW)
    {
        int h = wv >> 1, m = wv & 1;
        s16x8 a = *(const s16x8*)(psb + h * 1280 + (m * 16 + lr) * 40 + lg * 8);
        s16x8 b = *(const s16x8*)(vsT + (h * 16 + lr) * 40 + lg * 8);
        f32x4 acc = {0.f, 0.f, 0.f, 0.f};
        acc = __builtin_amdgcn_mfma_f32_16x16x32_bf16(a, b, acc, 0, 0, 0);
#pragma unroll
        for (int r = 0; r < 4; r++)
            ot[(m * 16 + lg * 4 + r) * 36 + h * 16 + lr] += acc[r];
    }
    __syncthreads();

    // proj: 4 MFMA + residual (re-read X) + scatter
    {
        int m = wv >> 1, n = wv & 1;
        union { s16x8 v; u16 h[8]; } a;
        const float* orow = ot + (m * 16 + lr) * 36 + lg * 8;
#pragma unroll
        for (int e = 0; e < 8; e++) a.h[e] = f2bf(orow[e]);
        s16x8 b = *(const s16x8*)(wprojB + ((n * 64 + l) << 3));
        f32x4 acc = {0.f, 0.f, 0.f, 0.f};
        acc = __builtin_amdgcn_mfma_f32_16x16x32_bf16(a.v, b, acc, 0, 0, 0);
        int c = n * 16 + lr;
        float bb = Pf[352 + c];
#pragma unroll
        for (int r = 0; r < 4; r++) {
            int tok = m * 16 + lg * 4 + r;
            int gi = win_idx[w * 32 + tok];
            out[(long)gi * 32 + c] = x[(long)gi * 32 + c] + bb + acc[r];
        }
    }
}

// ---- ws byte offsets ----
#define B_PF     0
#define B_FLAG   1536
#define B_ACTA   2048
#define B_ACTB   4196352
#define B_FEATS  8390656
#define B_WA1    8914944
#define B_WA2    8970240
#define B_WB1    9025536
#define B_WB2    9080832
#define B_WIN    9136128
#define B_WQKVB  9144320
#define B_WPROJB 9150464
#define B_TQBF   9152512
#define B_TKBF   9170944
#define B_TVBF   9189376

extern "C" void kernel_launch(void* const* d_in, const int* in_sizes, int n_in,
                              void* d_out, int out_size, void* d_ws, size_t ws_size,
                              hipStream_t stream) {
    const void* feats  = d_in[0];
    const int* pairs   = (const int*)d_in[1];
    const int* win_idx = (const int*)d_in[2];
    const int* rel_idx = (const int*)d_in[3];

    char* wsb = (char*)d_ws;
    float* Pf = (float*)(wsb + B_PF);
    int* flag = (int*)(wsb + B_FLAG);
    u16* actA = (u16*)(wsb + B_ACTA);
    u16* actB = (u16*)(wsb + B_ACTB);
    u16* fbf  = (u16*)(wsb + B_FEATS);
    u16* WpA1 = (u16*)(wsb + B_WA1);
    u16* WpA2 = (u16*)(wsb + B_WA2);
    u16* WpB1 = (u16*)(wsb + B_WB1);
    u16* WpB2 = (u16*)(wsb + B_WB2);
    u16* WpIN = (u16*)(wsb + B_WIN);
    u16* wqkvB  = (u16*)(wsb + B_WQKVB);
    u16* wprojB = (u16*)(wsb + B_WPROJB);
    u16* tqB = (u16*)(wsb + B_TQBF);
    u16* tkB = (u16*)(wsb + B_TKBF);
    u16* tvb = (u16*)(wsb + B_TVBF);
    float* X  = (float*)d_out;

    detect_kernel<<<1, 256, 0, stream>>>((const u32*)feats, flag);

    Ptrs pp;
    for (int i = 0; i < 24; i++) pp.p[i] = d_in[i];
    prep_all<<<dim3(1024, 9), 256, 0, stream>>>(pp, flag, fbf,
                                                WpA1, WpA2, WpB1, WpB2, WpIN,
                                                wqkvB, wprojB, tqB, tkB, tvb, Pf);

    convin_mfma<<<1024, 256, 0, stream>>>(fbf, pairs, WpIN, Pf + 0, X, actA);
    conv32_mfma<4><<<1024, 256, 0, stream>>>(actA, pairs, WpA1, Pf + 64,  X, actB);
    conv32_mfma<7><<<1024, 256, 0, stream>>>(actB, pairs, WpA2, Pf + 128, X, actA);
    conv32_mfma<4><<<1024, 256, 0, stream>>>(actA, pairs, WpB1, Pf + 192, X, actB);
    conv32_mfma<3><<<1024, 256, 0, stream>>>(actB, pairs, WpB2, Pf, X, actA);

    attn5_kernel<<<NWIN, 256, 0, stream>>>(X, win_idx, rel_idx,
                                           wqkvB, wprojB, Pf,
                                           tqB, tkB, tvb, X);
}

// Round 9
// 135.004 us; speedup vs baseline: 1.2471x; 1.0015x over previous
//
#include <hip/hip_runtime.h>

typedef unsigned short u16;
typedef unsigned int u32;

#define N_PTS 65536
#define KK 27
#define CIN 4
#define CC 32
#define NWIN 2048
#define CAP 32
#define NH 2
#define HD 16

typedef short s16x8 __attribute__((ext_vector_type(8)));
typedef float f32x4 __attribute__((ext_vector_type(4)));

__device__ __forceinline__ float bf2f(u16 h) { return __uint_as_float(((u32)h) << 16); }
__device__ __forceinline__ u16 f2bf(float f) {
    u32 u = __float_as_uint(f);
    u32 r = (u + 0x7FFFu + ((u >> 16) & 1u)) >> 16;
    return (u16)r;
}
__device__ __forceinline__ float ldany(const void* src, int i, bool isbf) {
    return isbf ? bf2f(((const u16*)src)[i]) : ((const float*)src)[i];
}
__device__ __forceinline__ u16 ldbf(const void* src, int i, bool isbf) {
    return isbf ? ((const u16*)src)[i] : f2bf(((const float*)src)[i]);
}

// ---- input float-dtype detection ----
__global__ void detect_kernel(const u32* __restrict__ w, int* flag) {
    int t = threadIdx.x;
    int cnt = 0;
    for (int i = t; i < 4096; i += 256) {
        u32 e = (w[i] >> 7) & 0xFFu;
        cnt += (e >= 100 && e <= 140) ? 1 : 0;
    }
    __shared__ int red[256];
    red[t] = cnt;
    __syncthreads();
    for (int s = 128; s > 0; s >>= 1) {
        if (t < s) red[t] += red[t + s];
        __syncthreads();
    }
    if (t == 0) flag[0] = (red[0] > 2048) ? 1 : 0;
}

// ---- single prep kernel ----
struct Ptrs { const void* p[24]; };

__global__ __launch_bounds__(256) void prep_all(
    Ptrs in, const int* __restrict__ flag,
    u16* __restrict__ fbf,
    u16* __restrict__ WpA1, u16* __restrict__ WpA2,
    u16* __restrict__ WpB1, u16* __restrict__ WpB2, u16* __restrict__ WpIN,
    u16* __restrict__ wqkvB, u16* __restrict__ wprojB,
    u16* __restrict__ tqB, u16* __restrict__ tkB, u16* __restrict__ tvb,
    float* __restrict__ Pf)
{
    bool isbf = flag[0] != 0;
    int seg = blockIdx.y;
    int i = blockIdx.x * 256 + threadIdx.x;
    if (seg == 0) {
        if (i < N_PTS * CIN) fbf[i] = ldbf(in.p[0], i, isbf);
        return;
    }
    if (seg <= 4) {
        if (i < 27648) {
            int e = i & 7, l = (i >> 3) & 63, dt = (i >> 9) & 1, k = i >> 10;
            const void* src = in.p[seg == 1 ? 7 : seg == 2 ? 10 : seg == 3 ? 13 : 16];
            u16* dst = seg == 1 ? WpA1 : seg == 2 ? WpA2 : seg == 3 ? WpB1 : WpB2;
            dst[i] = ldbf(src, k * 1024 + ((l >> 4) * 8 + e) * 32 + dt * 16 + (l & 15), isbf);
        }
        return;
    }
    if (seg == 5) {
        if (i < 4096) {
            int e = i & 7, l = (i >> 3) & 63, dt = (i >> 9) & 1, kk = i >> 10;
            int g = kk * 32 + (l >> 4) * 8 + e;
            int tp = g >> 2, c = g & 3;
            WpIN[i] = (tp < KK) ? ldbf(in.p[4], tp * 128 + c * 32 + dt * 16 + (l & 15), isbf) : (u16)0;
        }
        return;
    }
    if (seg == 6) {
        if (i < 3072) {
            int e = i & 7, l = (i >> 3) & 63, n = i >> 9;
            wqkvB[i] = ldbf(in.p[17], ((l >> 4) * 8 + e) * 96 + n * 16 + (l & 15), isbf);
        } else if (i < 4096) {
            int o2 = i - 3072;
            int e = o2 & 7, l = (o2 >> 3) & 63, n = o2 >> 9;
            wprojB[o2] = ldbf(in.p[19], ((l >> 4) * 8 + e) * 32 + n * 16 + (l & 15), isbf);
        }
        return;
    }
    if (seg == 7) {
        // tq/tk in MFMA B-fragment order; tv plain [144][32]
        if (i < 9216) {
            int e = i & 7, l = (i >> 3) & 63, nn = i >> 9;
            int n = nn % 9, h = nn / 9, lr = l & 15, lg = l >> 4;
            int k = lg * 8 + e;
            tqB[i] = (k < HD) ? ldbf(in.p[21], (n * 16 + lr) * 32 + h * 16 + k, isbf) : (u16)0;
        } else if (i < 18432) {
            int o2 = i - 9216;
            int e = o2 & 7, l = (o2 >> 3) & 63, nn = o2 >> 9;
            int n = nn % 9, h = nn / 9, lr = l & 15, lg = l >> 4;
            int k = lg * 8 + e;
            tkB[o2] = (k < HD) ? ldbf(in.p[22], (n * 16 + lr) * 32 + h * 16 + k, isbf) : (u16)0;
        } else if (i < 23040) {
            int o2 = i - 18432;
            tvb[o2] = ldbf(in.p[23], o2, isbf);
        }
        return;
    }
    // seg 8: GB(8x32) | bqkv(96)@256 | bproj(32)@352
    if (i < 256) {
        const int srcs[8] = {5, 6, 8, 9, 11, 12, 14, 15};
        Pf[i] = ldany(in.p[srcs[i >> 5]], i & 31, isbf);
    } else if (i < 352) {
        Pf[i] = ldany(in.p[18], i - 256, isbf);
    } else if (i < 384) {
        Pf[i] = ldany(in.p[20], i - 352, isbf);
    }
}

// ---- MFMA input conv: batch-load phase then compute phase ----
__global__ __launch_bounds__(256) void convin_mfma(
    const u16* __restrict__ fb, const int* __restrict__ pairs,
    const u16* __restrict__ Wp, const float* __restrict__ gb,
    float* __restrict__ xbuf, u16* __restrict__ act_out)
{
    int t = threadIdx.x;
    int wv = t >> 6, l = t & 63;
    int lr = l & 15, lg = l >> 4;
    int p0 = (blockIdx.x * 4 + wv) * 16;
    int rowaddr = p0 + lr;

    // phase 1: issue ALL loads (idx -> gathers; weights independent)
    int ia[4], ib[4];
    u32 ma[4], mb[4];
#pragma unroll
    for (int kk = 0; kk < 4; kk++) {
        int t0 = kk * 8 + lg * 2;
        int ta = t0 < 26 ? t0 : 26;
        int tb = (t0 + 1) < 26 ? (t0 + 1) : 26;
        ia[kk] = pairs[ta * N_PTS + rowaddr];
        ib[kk] = pairs[tb * N_PTS + rowaddr];
        ma[kk] = (t0 < KK && ia[kk] >= 0) ? 0xFFFFFFFFu : 0u;
        mb[kk] = (t0 + 1 < KK && ib[kk] >= 0) ? 0xFFFFFFFFu : 0u;
    }
    uint2 qa[4], qb[4];
    s16x8 b0[4], b1[4];
#pragma unroll
    for (int kk = 0; kk < 4; kk++) {
        qa[kk] = *(const uint2*)(fb + (long)(ia[kk] < 0 ? 0 : ia[kk]) * CIN);
        qb[kk] = *(const uint2*)(fb + (long)(ib[kk] < 0 ? 0 : ib[kk]) * CIN);
        const s16x8* wb = (const s16x8*)Wp + kk * 128 + l;
        b0[kk] = wb[0];
        b1[kk] = wb[64];
    }

    f32x4 acc0 = {0.f, 0.f, 0.f, 0.f}, acc1 = {0.f, 0.f, 0.f, 0.f};
#pragma unroll
    for (int kk = 0; kk < 4; kk++) {
        union { uint4 q; s16x8 v; } a;
        a.q = make_uint4(qa[kk].x & ma[kk], qa[kk].y & ma[kk],
                         qb[kk].x & mb[kk], qb[kk].y & mb[kk]);
        acc0 = __builtin_amdgcn_mfma_f32_16x16x32_bf16(a.v, b0[kk], acc0, 0, 0, 0);
        acc1 = __builtin_amdgcn_mfma_f32_16x16x32_bf16(a.v, b1[kk], acc1, 0, 0, 0);
    }
    float g0 = gb[lr], b0v = gb[32 + lr], g1 = gb[16 + lr], b1v = gb[48 + lr];
#pragma unroll
    for (int r = 0; r < 4; r++) {
        int row = p0 + lg * 4 + r;
        long o0 = (long)row * 32 + lr, o1 = o0 + 16;
        float v0 = acc0[r], v1 = acc1[r];
        xbuf[o0] = v0; xbuf[o1] = v1;
        act_out[o0] = f2bf(fmaxf(fmaf(v0, g0, b0v), 0.f));
        act_out[o1] = f2bf(fmaxf(fmaf(v1, g1, b1v), 0.f));
    }
}

// ---- MFMA 32->32 gather conv; 8-deep ring prefetch of gather AND weights ----
// M: bit0 READ_X, bit1 WRITE_X, bit2 WRITE_ACT
template <int M>
__global__ __launch_bounds__(256) void conv32_mfma(
    const u16* __restrict__ act_in, const int* __restrict__ pairs,
    const u16* __restrict__ Wp, const float* __restrict__ gb,
    float* __restrict__ xbuf, u16* __restrict__ act_out)
{
    int t = threadIdx.x;
    int wv = t >> 6, l = t & 63;
    int lr = l & 15, lg = l >> 4;
    int p0 = (blockIdx.x * 4 + wv) * 16;
    int rowaddr = p0 + lr;

    int idx[KK];
#pragma unroll
    for (int k = 0; k < KK; k++) idx[k] = pairs[k * N_PTS + rowaddr];

    // ring of {gather, weight0, weight1} triples — consecutive issue order so
    // the wait before MFMA(k) is a counted vmcnt (~21), never a full drain
    uint4 qr[8];
    s16x8 b0r[8], b1r[8];
#pragma unroll
    for (int k = 0; k < 8; k++) {
        int ic = idx[k] < 0 ? 0 : idx[k];
        qr[k] = *(const uint4*)(act_in + (long)ic * CC + lg * 8);
        const s16x8* wb = (const s16x8*)Wp + k * 128 + l;
        b0r[k] = wb[0];
        b1r[k] = wb[64];
    }

    f32x4 acc0 = {0.f, 0.f, 0.f, 0.f}, acc1 = {0.f, 0.f, 0.f, 0.f};
#pragma unroll
    for (int k = 0; k < KK; k++) {
        int s = k & 7;
        uint4 q = qr[s];
        s16x8 w0 = b0r[s];
        s16x8 w1 = b1r[s];
        if (k + 8 < KK) {
            int kn = k + 8;
            int ic = idx[kn] < 0 ? 0 : idx[kn];
            qr[s] = *(const uint4*)(act_in + (long)ic * CC + lg * 8);
            const s16x8* wb = (const s16x8*)Wp + kn * 128 + l;
            b0r[s] = wb[0];
            b1r[s] = wb[64];
        }
        u32 msk = idx[k] >= 0 ? 0xFFFFFFFFu : 0u;
        q.x &= msk; q.y &= msk; q.z &= msk; q.w &= msk;
        union { uint4 q; s16x8 v; } a;
        a.q = q;
        acc0 = __builtin_amdgcn_mfma_f32_16x16x32_bf16(a.v, w0, acc0, 0, 0, 0);
        acc1 = __builtin_amdgcn_mfma_f32_16x16x32_bf16(a.v, w1, acc1, 0, 0, 0);
    }
    float g0 = 0.f, b0v = 0.f, g1 = 0.f, b1v = 0.f;
    if (M & 4) { g0 = gb[lr]; b0v = gb[32 + lr]; g1 = gb[16 + lr]; b1v = gb[48 + lr]; }
#pragma unroll
    for (int r = 0; r < 4; r++) {
        int row = p0 + lg * 4 + r;
        long o0 = (long)row * 32 + lr, o1 = o0 + 16;
        float v0 = acc0[r], v1 = acc1[r];
        if (M & 1) { v0 += xbuf[o0]; v1 += xbuf[o1]; }
        if (M & 2) { xbuf[o0] = v0; xbuf[o1] = v1; }
        if (M & 4) {
            act_out[o0] = f2bf(fmaxf(fmaf(v0, g0, b0v), 0.f));
            act_out[o1] = f2bf(fmaxf(fmaf(v1, g1, b1v), 0.f));
        }
    }
}

// ---- attention v5 (unchanged from round 8) ----
#define A5_RIDX 0
#define A5_QSB  4096
#define A5_KSB  6656
#define A5_VST  9216
#define A5_SC   11776
#define A5_BQ   20992
#define A5_BK   30208
#define A5_SIZE 39424

__global__ __launch_bounds__(256) void attn5_kernel(
    const float* __restrict__ x, const int* __restrict__ win_idx,
    const int* __restrict__ rel_idx,
    const u16* __restrict__ wqkvB, const u16* __restrict__ wprojB,
    const float* __restrict__ Pf,
    const u16* __restrict__ tqB, const u16* __restrict__ tkB, const u16* __restrict__ tvb,
    float* __restrict__ out)
{
    __shared__ __align__(16) char arena[A5_SIZE];
    int*   ridx = (int*)(arena + A5_RIDX);
    u16*   qsb  = (u16*)(arena + A5_QSB);
    u16*   ksb  = (u16*)(arena + A5_KSB);
    u16*   vsT  = (u16*)(arena + A5_VST);
    float* sc   = (float*)(arena + A5_SC);
    u16*   psb  = (u16*)(arena + A5_SC);
    u16*   Bq   = (u16*)(arena + A5_BQ);
    u16*   Bk   = (u16*)(arena + A5_BK);
    float* ot   = (float*)(arena + A5_BQ);

    int w = blockIdx.x, t = threadIdx.x;
    int wv = t >> 6, l = t & 63, lr = l & 15, lg = l >> 4;

    {
        int4 r4 = *(const int4*)(rel_idx + (long)w * 1024 + t * 4);
        *(int4*)(ridx + t * 4) = r4;
    }
    {
        const float* bqkv = Pf + 256;
        for (int pi = wv; pi < 12; pi += 4) {
            int n = pi >> 1, m = pi & 1;
            int gi = win_idx[w * 32 + m * 16 + lr];
            const float* xr = x + (long)gi * 32 + lg * 8;
            float4 x0 = *(const float4*)(xr);
            float4 x1 = *(const float4*)(xr + 4);
            union { s16x8 v; u16 h[8]; } a;
            a.h[0] = f2bf(x0.x); a.h[1] = f2bf(x0.y); a.h[2] = f2bf(x0.z); a.h[3] = f2bf(x0.w);
            a.h[4] = f2bf(x1.x); a.h[5] = f2bf(x1.y); a.h[6] = f2bf(x1.z); a.h[7] = f2bf(x1.w);
            s16x8 b = *(const s16x8*)(wqkvB + ((n * 64 + l) << 3));
            f32x4 acc = {0.f, 0.f, 0.f, 0.f};
            acc = __builtin_amdgcn_mfma_f32_16x16x32_bf16(a.v, b, acc, 0, 0, 0);
            int tt = n * 16 + lr;
            float bias = bqkv[tt];
#pragma unroll
            for (int r = 0; r < 4; r++) {
                int tok = m * 16 + lg * 4 + r;
                float v = acc[r] + bias;
                if (tt < 32)      qsb[tok * 40 + tt] = f2bf(v * 0.25f);
                else if (tt < 64) ksb[tok * 40 + (tt - 32)] = f2bf(v);
                else              vsT[(tt - 64) * 40 + tok] = f2bf(v);
            }
        }
    }
    __syncthreads();

    for (int h = 0; h < NH; h++) {
        for (int pi = wv; pi < 36; pi += 4) {
            int tb = pi >= 18 ? 1 : 0;
            int rem = pi - tb * 18;
            int m = rem / 9, n = rem % 9;
            const u16* src = tb ? ksb : qsb;
            const u16* tab = tb ? tkB : tqB;
            s16x8 a = {0, 0, 0, 0, 0, 0, 0, 0};
            if (lg < 2) a = *(const s16x8*)(src + (m * 16 + lr) * 40 + h * 16 + lg * 8);
            s16x8 b = *(const s16x8*)(tab + (((h * 9 + n) * 64 + l) << 3));
            f32x4 acc = {0.f, 0.f, 0.f, 0.f};
            acc = __builtin_amdgcn_mfma_f32_16x16x32_bf16(a, b, acc, 0, 0, 0);
            u16* dst = tb ? Bk : Bq;
#pragma unroll
            for (int r = 0; r < 4; r++)
                dst[(m * 16 + lg * 4 + r) * 144 + n * 16 + lr] = f2bf(acc[r]);
        }
        __syncthreads();
        for (int e = t; e < 1024; e += 256) {
            int i = e >> 5, j = e & 31, r = ridx[e];
            sc[h * 1152 + i * 36 + j] = bf2f(Bq[i * 144 + r]) + bf2f(Bk[j * 144 + r]);
        }
        __syncthreads();
    }

    for (int pi = wv; pi < 8; pi += 4) {
        int h = pi >> 2, m = (pi >> 1) & 1, n = pi & 1;
        s16x8 a = {0, 0, 0, 0, 0, 0, 0, 0}, b = {0, 0, 0, 0, 0, 0, 0, 0};
        if (lg < 2) {
            a = *(const s16x8*)(qsb + (m * 16 + lr) * 40 + h * 16 + lg * 8);
            b = *(const s16x8*)(ksb + (n * 16 + lr) * 40 + h * 16 + lg * 8);
        }
        f32x4 acc = {0.f, 0.f, 0.f, 0.f};
        acc = __builtin_amdgcn_mfma_f32_16x16x32_bf16(a, b, acc, 0, 0, 0);
#pragma unroll
        for (int r = 0; r < 4; r++)
            sc[h * 1152 + (m * 16 + lg * 4 + r) * 36 + n * 16 + lr] += acc[r];
    }
    __syncthreads();

    {
        int rr = t >> 2, sub = t & 3;
        int h = rr >> 5, i = rr & 31, j0 = sub * 8;
        const float* srow = sc + h * 1152 + i * 36 + j0;
        float pv[8];
        float m_ = -1e30f;
#pragma unroll
        for (int jj = 0; jj < 8; jj++) { pv[jj] = srow[jj]; m_ = fmaxf(m_, pv[jj]); }
        m_ = fmaxf(m_, __shfl_xor(m_, 1));
        m_ = fmaxf(m_, __shfl_xor(m_, 2));
        float sum = 0.f;
#pragma unroll
        for (int jj = 0; jj < 8; jj++) { pv[jj] = __expf(pv[jj] - m_); sum += pv[jj]; }
        sum += __shfl_xor(sum, 1);
        sum += __shfl_xor(sum, 2);
        float inv = 1.f / sum;
        __syncthreads();
        u16* prow = psb + h * 1280 + i * 40 + j0;
#pragma unroll
        for (int jj = 0; jj < 8; jj++) prow[jj] = f2bf(pv[jj] * inv);
    }
    __syncthreads();

    for (int o = t; o < CAP * 16; o += 256) {
        int i = o >> 4, hp = o & 15, h = hp >> 3;
        const u16* prow = psb + h * 1280 + i * 40;
        const int* rrow = ridx + i * 32;
        float a0 = 0.f, a1 = 0.f;
#pragma unroll 8
        for (int j = 0; j < CAP; j++) {
            int r = rrow[j];
            float p = bf2f(prow[j]);
            u32 tv2 = *(const u32*)(tvb + r * 32 + hp * 2);
            a0 = fmaf(p, __uint_as_float(tv2 << 16), a0);
            a1 = fmaf(p, __uint_as_float(tv2 & 0xffff0000u), a1);
        }
        ot[i * 36 + hp * 2] = a0;
        ot[i * 36 + hp * 2 + 1] = a1;
    }
    __syncthreads();

    {
        int h = wv >> 1, m = wv & 1;
        s16x8 a = *(const s16x8*)(psb + h * 1280 + (m * 16 + lr) * 40 + lg * 8);
        s16x8 b = *(const s16x8*)(vsT + (h * 16 + lr) * 40 + lg * 8);
        f32x4 acc = {0.f, 0.f, 0.f, 0.f};
        acc = __builtin_amdgcn_mfma_f32_16x16x32_bf16(a, b, acc, 0, 0, 0);
#pragma unroll
        for (int r = 0; r < 4; r++)
            ot[(m * 16 + lg * 4 + r) * 36 + h * 16 + lr] += acc[r];
    }
    __syncthreads();

    {
        int m = wv >> 1, n = wv & 1;
        union { s16x8 v; u16 h[8]; } a;
        const float* orow = ot + (m * 16 + lr) * 36 + lg * 8;
#pragma unroll
        for (int e = 0; e < 8; e++) a.h[e] = f2bf(orow[e]);
        s16x8 b = *(const s16x8*)(wprojB + ((n * 64 + l) << 3));
        f32x4 acc = {0.f, 0.f, 0.f, 0.f};
        acc = __builtin_amdgcn_mfma_f32_16x16x32_bf16(a.v, b, acc, 0, 0, 0);
        int c = n * 16 + lr;
        float bb = Pf[352 + c];
#pragma unroll
        for (int r = 0; r < 4; r++) {
            int tok = m * 16 + lg * 4 + r;
            int gi = win_idx[w * 32 + tok];
            out[(long)gi * 32 + c] = x[(long)gi * 32 + c] + bb + acc[r];
        }
    }
}

// ---- ws byte offsets ----
#define B_PF     0
#define B_FLAG   1536
#define B_ACTA   2048
#define B_ACTB   4196352
#define B_FEATS  8390656
#define B_WA1    8914944
#define B_WA2    8970240
#define B_WB1    9025536
#define B_WB2    9080832
#define B_WIN    9136128
#define B_WQKVB  9144320
#define B_WPROJB 9150464
#define B_TQBF   9152512
#define B_TKBF   9170944
#define B_TVBF   9189376

extern "C" void kernel_launch(void* const* d_in, const int* in_sizes, int n_in,
                              void* d_out, int out_size, void* d_ws, size_t ws_size,
                              hipStream_t stream) {
    const void* feats  = d_in[0];
    const int* pairs   = (const int*)d_in[1];
    const int* win_idx = (const int*)d_in[2];
    const int* rel_idx = (const int*)d_in[3];

    char* wsb = (char*)d_ws;
    float* Pf = (float*)(wsb + B_PF);
    int* flag = (int*)(wsb + B_FLAG);
    u16* actA = (u16*)(wsb + B_ACTA);
    u16* actB = (u16*)(wsb + B_ACTB);
    u16* fbf  = (u16*)(wsb + B_FEATS);
    u16* WpA1 = (u16*)(wsb + B_WA1);
    u16* WpA2 = (u16*)(wsb + B_WA2);
    u16* WpB1 = (u16*)(wsb + B_WB1);
    u16* WpB2 = (u16*)(wsb + B_WB2);
    u16* WpIN = (u16*)(wsb + B_WIN);
    u16* wqkvB  = (u16*)(wsb + B_WQKVB);
    u16* wprojB = (u16*)(wsb + B_WPROJB);
    u16* tqB = (u16*)(wsb + B_TQBF);
    u16* tkB = (u16*)(wsb + B_TKBF);
    u16* tvb = (u16*)(wsb + B_TVBF);
    float* X  = (float*)d_out;

    detect_kernel<<<1, 256, 0, stream>>>((const u32*)feats, flag);

    Ptrs pp;
    for (int i = 0; i < 24; i++) pp.p[i] = d_in[i];
    prep_all<<<dim3(1024, 9), 256, 0, stream>>>(pp, flag, fbf,
                                                WpA1, WpA2, WpB1, WpB2, WpIN,
                                                wqkvB, wprojB, tqB, tkB, tvb, Pf);

    convin_mfma<<<1024, 256, 0, stream>>>(fbf, pairs, WpIN, Pf + 0, X, actA);
    conv32_mfma<4><<<1024, 256, 0, stream>>>(actA, pairs, WpA1, Pf + 64,  X, actB);
    conv32_mfma<7><<<1024, 256, 0, stream>>>(actB, pairs, WpA2, Pf + 128, X, actA);
    conv32_mfma<4><<<1024, 256, 0, stream>>>(actA, pairs, WpB1, Pf + 192, X, actB);
    conv32_mfma<3><<<1024, 256, 0, stream>>>(actB, pairs, WpB2, Pf, X, actA);

    attn5_kernel<<<NWIN, 256, 0, stream>>>(X, win_idx, rel_idx,
                                           wqkvB, wprojB, Pf,
                                           tqB, tkB, tvb, X);
}

// Round 10
// 127.131 us; speedup vs baseline: 1.3243x; 1.0619x over previous
//
#include <hip/hip_runtime.h>

typedef unsigned short u16;
typedef unsigned int u32;

#define N_PTS 65536
#define KK 27
#define CIN 4
#define CC 32
#define NWIN 2048
#define CAP 32
#define NH 2
#define HD 16

typedef short s16x8 __attribute__((ext_vector_type(8)));
typedef float f32x4 __attribute__((ext_vector_type(4)));

__device__ __forceinline__ float bf2f(u16 h) { return __uint_as_float(((u32)h) << 16); }
__device__ __forceinline__ u16 f2bf(float f) {
    u32 u = __float_as_uint(f);
    u32 r = (u + 0x7FFFu + ((u >> 16) & 1u)) >> 16;
    return (u16)r;
}
__device__ __forceinline__ float ldany(const void* src, int i, bool isbf) {
    return isbf ? bf2f(((const u16*)src)[i]) : ((const float*)src)[i];
}
__device__ __forceinline__ u16 ldbf(const void* src, int i, bool isbf) {
    return isbf ? ((const u16*)src)[i] : f2bf(((const float*)src)[i]);
}

// ---- input float-dtype detection ----
__global__ void detect_kernel(const u32* __restrict__ w, int* flag) {
    int t = threadIdx.x;
    int cnt = 0;
    for (int i = t; i < 4096; i += 256) {
        u32 e = (w[i] >> 7) & 0xFFu;
        cnt += (e >= 100 && e <= 140) ? 1 : 0;
    }
    __shared__ int red[256];
    red[t] = cnt;
    __syncthreads();
    for (int s = 128; s > 0; s >>= 1) {
        if (t < s) red[t] += red[t + s];
        __syncthreads();
    }
    if (t == 0) flag[0] = (red[0] > 2048) ? 1 : 0;
}

// ---- single prep kernel ----
struct Ptrs { const void* p[24]; };

__global__ __launch_bounds__(256) void prep_all(
    Ptrs in, const int* __restrict__ flag,
    u16* __restrict__ fbf,
    u16* __restrict__ WpA1, u16* __restrict__ WpA2,
    u16* __restrict__ WpB1, u16* __restrict__ WpB2, u16* __restrict__ WpIN,
    u16* __restrict__ wqkvB, u16* __restrict__ wprojB,
    u16* __restrict__ tqB, u16* __restrict__ tkB, u16* __restrict__ tvb,
    float* __restrict__ Pf)
{
    bool isbf = flag[0] != 0;
    int seg = blockIdx.y;
    int i = blockIdx.x * 256 + threadIdx.x;
    if (seg == 0) {
        if (i < N_PTS * CIN) fbf[i] = ldbf(in.p[0], i, isbf);
        return;
    }
    if (seg <= 4) {
        if (i < 27648) {
            int e = i & 7, l = (i >> 3) & 63, dt = (i >> 9) & 1, k = i >> 10;
            const void* src = in.p[seg == 1 ? 7 : seg == 2 ? 10 : seg == 3 ? 13 : 16];
            u16* dst = seg == 1 ? WpA1 : seg == 2 ? WpA2 : seg == 3 ? WpB1 : WpB2;
            dst[i] = ldbf(src, k * 1024 + ((l >> 4) * 8 + e) * 32 + dt * 16 + (l & 15), isbf);
        }
        return;
    }
    if (seg == 5) {
        if (i < 4096) {
            int e = i & 7, l = (i >> 3) & 63, dt = (i >> 9) & 1, kk = i >> 10;
            int g = kk * 32 + (l >> 4) * 8 + e;
            int tp = g >> 2, c = g & 3;
            WpIN[i] = (tp < KK) ? ldbf(in.p[4], tp * 128 + c * 32 + dt * 16 + (l & 15), isbf) : (u16)0;
        }
        return;
    }
    if (seg == 6) {
        if (i < 3072) {
            int e = i & 7, l = (i >> 3) & 63, n = i >> 9;
            wqkvB[i] = ldbf(in.p[17], ((l >> 4) * 8 + e) * 96 + n * 16 + (l & 15), isbf);
        } else if (i < 4096) {
            int o2 = i - 3072;
            int e = o2 & 7, l = (o2 >> 3) & 63, n = o2 >> 9;
            wprojB[o2] = ldbf(in.p[19], ((l >> 4) * 8 + e) * 32 + n * 16 + (l & 15), isbf);
        }
        return;
    }
    if (seg == 7) {
        // tq/tk in MFMA B-fragment order; tv plain [144][32]
        if (i < 9216) {
            int e = i & 7, l = (i >> 3) & 63, nn = i >> 9;
            int n = nn % 9, h = nn / 9, lr = l & 15, lg = l >> 4;
            int k = lg * 8 + e;
            tqB[i] = (k < HD) ? ldbf(in.p[21], (n * 16 + lr) * 32 + h * 16 + k, isbf) : (u16)0;
        } else if (i < 18432) {
            int o2 = i - 9216;
            int e = o2 & 7, l = (o2 >> 3) & 63, nn = o2 >> 9;
            int n = nn % 9, h = nn / 9, lr = l & 15, lg = l >> 4;
            int k = lg * 8 + e;
            tkB[o2] = (k < HD) ? ldbf(in.p[22], (n * 16 + lr) * 32 + h * 16 + k, isbf) : (u16)0;
        } else if (i < 23040) {
            int o2 = i - 18432;
            tvb[o2] = ldbf(in.p[23], o2, isbf);
        }
        return;
    }
    // seg 8: GB(8x32) | bqkv(96)@256 | bproj(32)@352
    if (i < 256) {
        const int srcs[8] = {5, 6, 8, 9, 11, 12, 14, 15};
        Pf[i] = ldany(in.p[srcs[i >> 5]], i & 31, isbf);
    } else if (i < 352) {
        Pf[i] = ldany(in.p[18], i - 256, isbf);
    } else if (i < 384) {
        Pf[i] = ldany(in.p[20], i - 352, isbf);
    }
}

// ---- MFMA input conv: batch-load phase then compute phase ----
__global__ __launch_bounds__(256) void convin_mfma(
    const u16* __restrict__ fb, const int* __restrict__ pairs,
    const u16* __restrict__ Wp, const float* __restrict__ gb,
    float* __restrict__ xbuf, u16* __restrict__ act_out)
{
    int t = threadIdx.x;
    int wv = t >> 6, l = t & 63;
    int lr = l & 15, lg = l >> 4;
    int p0 = (blockIdx.x * 4 + wv) * 16;
    int rowaddr = p0 + lr;

    int ia[4], ib[4];
    u32 ma[4], mb[4];
#pragma unroll
    for (int kk = 0; kk < 4; kk++) {
        int t0 = kk * 8 + lg * 2;
        int ta = t0 < 26 ? t0 : 26;
        int tb = (t0 + 1) < 26 ? (t0 + 1) : 26;
        ia[kk] = pairs[ta * N_PTS + rowaddr];
        ib[kk] = pairs[tb * N_PTS + rowaddr];
        ma[kk] = (t0 < KK && ia[kk] >= 0) ? 0xFFFFFFFFu : 0u;
        mb[kk] = (t0 + 1 < KK && ib[kk] >= 0) ? 0xFFFFFFFFu : 0u;
    }
    uint2 qa[4], qb[4];
    s16x8 b0[4], b1[4];
#pragma unroll
    for (int kk = 0; kk < 4; kk++) {
        qa[kk] = *(const uint2*)(fb + (long)(ia[kk] < 0 ? 0 : ia[kk]) * CIN);
        qb[kk] = *(const uint2*)(fb + (long)(ib[kk] < 0 ? 0 : ib[kk]) * CIN);
        const s16x8* wb = (const s16x8*)Wp + kk * 128 + l;
        b0[kk] = wb[0];
        b1[kk] = wb[64];
    }

    f32x4 acc0 = {0.f, 0.f, 0.f, 0.f}, acc1 = {0.f, 0.f, 0.f, 0.f};
#pragma unroll
    for (int kk = 0; kk < 4; kk++) {
        union { uint4 q; s16x8 v; } a;
        a.q = make_uint4(qa[kk].x & ma[kk], qa[kk].y & ma[kk],
                         qb[kk].x & mb[kk], qb[kk].y & mb[kk]);
        acc0 = __builtin_amdgcn_mfma_f32_16x16x32_bf16(a.v, b0[kk], acc0, 0, 0, 0);
        acc1 = __builtin_amdgcn_mfma_f32_16x16x32_bf16(a.v, b1[kk], acc1, 0, 0, 0);
    }
    float g0 = gb[lr], b0v = gb[32 + lr], g1 = gb[16 + lr], b1v = gb[48 + lr];
#pragma unroll
    for (int r = 0; r < 4; r++) {
        int row = p0 + lg * 4 + r;
        long o0 = (long)row * 32 + lr, o1 = o0 + 16;
        float v0 = acc0[r], v1 = acc1[r];
        xbuf[o0] = v0; xbuf[o1] = v1;
        act_out[o0] = f2bf(fmaxf(fmaf(v0, g0, b0v), 0.f));
        act_out[o1] = f2bf(fmaxf(fmaf(v1, g1, b1v), 0.f));
    }
}

// ---- MFMA 32->32 gather conv; weights staged ONCE per block in LDS ----
// grid 512; each wave computes 2 sequential 16-row tiles (block = 128 rows).
// Weight L2 traffic: 512 blocks x 55KB = 28 MB (was 226 MB at 1 load/wave).
// Gathers keep the 8-deep ring; they are now the ONLY vmcnt ops in the loop.
// M: bit0 READ_X, bit1 WRITE_X, bit2 WRITE_ACT
template <int M>
__global__ __launch_bounds__(256) void conv32_lds(
    const u16* __restrict__ act_in, const int* __restrict__ pairs,
    const u16* __restrict__ Wp, const float* __restrict__ gb,
    float* __restrict__ xbuf, u16* __restrict__ act_out)
{
    __shared__ u16 wlds[KK * 1024];   // 55296 B
    int t = threadIdx.x;
    int wv = t >> 6, l = t & 63;
    int lr = l & 15, lg = l >> 4;

    // cooperative coalesced stage: 3456 uint4
    {
        const uint4* src = (const uint4*)Wp;
        uint4* dst = (uint4*)wlds;
#pragma unroll
        for (int q = 0; q < 14; q++) {
            int e = q * 256 + t;
            if (e < 3456) dst[e] = src[e];
        }
    }
    __syncthreads();

    float g0 = 0.f, b0v = 0.f, g1 = 0.f, b1v = 0.f;
    if (M & 4) { g0 = gb[lr]; b0v = gb[32 + lr]; g1 = gb[16 + lr]; b1v = gb[48 + lr]; }

#pragma unroll
    for (int tile = 0; tile < 2; tile++) {
        int p0 = ((blockIdx.x * 4 + wv) * 2 + tile) * 16;
        int rowaddr = p0 + lr;

        int idx[KK];
#pragma unroll
        for (int k = 0; k < KK; k++) idx[k] = pairs[k * N_PTS + rowaddr];

        uint4 qr[8];
#pragma unroll
        for (int k = 0; k < 8; k++) {
            int ic = idx[k] < 0 ? 0 : idx[k];
            qr[k] = *(const uint4*)(act_in + (long)ic * CC + lg * 8);
        }

        f32x4 acc0 = {0.f, 0.f, 0.f, 0.f}, acc1 = {0.f, 0.f, 0.f, 0.f};
#pragma unroll
        for (int k = 0; k < KK; k++) {
            int s = k & 7;
            uint4 q = qr[s];
            if (k + 8 < KK) {
                int kn = k + 8;
                int ic = idx[kn] < 0 ? 0 : idx[kn];
                qr[s] = *(const uint4*)(act_in + (long)ic * CC + lg * 8);
            }
            u32 msk = idx[k] >= 0 ? 0xFFFFFFFFu : 0u;
            q.x &= msk; q.y &= msk; q.z &= msk; q.w &= msk;
            union { uint4 q; s16x8 v; } a;
            a.q = q;
            const s16x8* wb = (const s16x8*)wlds + k * 128 + l;
            s16x8 w0 = wb[0];
            s16x8 w1 = wb[64];
            acc0 = __builtin_amdgcn_mfma_f32_16x16x32_bf16(a.v, w0, acc0, 0, 0, 0);
            acc1 = __builtin_amdgcn_mfma_f32_16x16x32_bf16(a.v, w1, acc1, 0, 0, 0);
        }
#pragma unroll
        for (int r = 0; r < 4; r++) {
            int row = p0 + lg * 4 + r;
            long o0 = (long)row * 32 + lr, o1 = o0 + 16;
            float v0 = acc0[r], v1 = acc1[r];
            if (M & 1) { v0 += xbuf[o0]; v1 += xbuf[o1]; }
            if (M & 2) { xbuf[o0] = v0; xbuf[o1] = v1; }
            if (M & 4) {
                act_out[o0] = f2bf(fmaxf(fmaf(v0, g0, b0v), 0.f));
                act_out[o1] = f2bf(fmaxf(fmaf(v1, g1, b1v), 0.f));
            }
        }
    }
}

// ---- attention v5 (unchanged) ----
#define A5_RIDX 0
#define A5_QSB  4096
#define A5_KSB  6656
#define A5_VST  9216
#define A5_SC   11776
#define A5_BQ   20992
#define A5_BK   30208
#define A5_SIZE 39424

__global__ __launch_bounds__(256) void attn5_kernel(
    const float* __restrict__ x, const int* __restrict__ win_idx,
    const int* __restrict__ rel_idx,
    const u16* __restrict__ wqkvB, const u16* __restrict__ wprojB,
    const float* __restrict__ Pf,
    const u16* __restrict__ tqB, const u16* __restrict__ tkB, const u16* __restrict__ tvb,
    float* __restrict__ out)
{
    __shared__ __align__(16) char arena[A5_SIZE];
    int*   ridx = (int*)(arena + A5_RIDX);
    u16*   qsb  = (u16*)(arena + A5_QSB);
    u16*   ksb  = (u16*)(arena + A5_KSB);
    u16*   vsT  = (u16*)(arena + A5_VST);
    float* sc   = (float*)(arena + A5_SC);
    u16*   psb  = (u16*)(arena + A5_SC);
    u16*   Bq   = (u16*)(arena + A5_BQ);
    u16*   Bk   = (u16*)(arena + A5_BK);
    float* ot   = (float*)(arena + A5_BQ);

    int w = blockIdx.x, t = threadIdx.x;
    int wv = t >> 6, l = t & 63, lr = l & 15, lg = l >> 4;

    {
        int4 r4 = *(const int4*)(rel_idx + (long)w * 1024 + t * 4);
        *(int4*)(ridx + t * 4) = r4;
    }
    {
        const float* bqkv = Pf + 256;
        for (int pi = wv; pi < 12; pi += 4) {
            int n = pi >> 1, m = pi & 1;
            int gi = win_idx[w * 32 + m * 16 + lr];
            const float* xr = x + (long)gi * 32 + lg * 8;
            float4 x0 = *(const float4*)(xr);
            float4 x1 = *(const float4*)(xr + 4);
            union { s16x8 v; u16 h[8]; } a;
            a.h[0] = f2bf(x0.x); a.h[1] = f2bf(x0.y); a.h[2] = f2bf(x0.z); a.h[3] = f2bf(x0.w);
            a.h[4] = f2bf(x1.x); a.h[5] = f2bf(x1.y); a.h[6] = f2bf(x1.z); a.h[7] = f2bf(x1.w);
            s16x8 b = *(const s16x8*)(wqkvB + ((n * 64 + l) << 3));
            f32x4 acc = {0.f, 0.f, 0.f, 0.f};
            acc = __builtin_amdgcn_mfma_f32_16x16x32_bf16(a.v, b, acc, 0, 0, 0);
            int tt = n * 16 + lr;
            float bias = bqkv[tt];
#pragma unroll
            for (int r = 0; r < 4; r++) {
                int tok = m * 16 + lg * 4 + r;
                float v = acc[r] + bias;
                if (tt < 32)      qsb[tok * 40 + tt] = f2bf(v * 0.25f);
                else if (tt < 64) ksb[tok * 40 + (tt - 32)] = f2bf(v);
                else              vsT[(tt - 64) * 40 + tok] = f2bf(v);
            }
        }
    }
    __syncthreads();

    for (int h = 0; h < NH; h++) {
        for (int pi = wv; pi < 36; pi += 4) {
            int tb = pi >= 18 ? 1 : 0;
            int rem = pi - tb * 18;
            int m = rem / 9, n = rem % 9;
            const u16* src = tb ? ksb : qsb;
            const u16* tab = tb ? tkB : tqB;
            s16x8 a = {0, 0, 0, 0, 0, 0, 0, 0};
            if (lg < 2) a = *(const s16x8*)(src + (m * 16 + lr) * 40 + h * 16 + lg * 8);
            s16x8 b = *(const s16x8*)(tab + (((h * 9 + n) * 64 + l) << 3));
            f32x4 acc = {0.f, 0.f, 0.f, 0.f};
            acc = __builtin_amdgcn_mfma_f32_16x16x32_bf16(a, b, acc, 0, 0, 0);
            u16* dst = tb ? Bk : Bq;
#pragma unroll
            for (int r = 0; r < 4; r++)
                dst[(m * 16 + lg * 4 + r) * 144 + n * 16 + lr] = f2bf(acc[r]);
        }
        __syncthreads();
        for (int e = t; e < 1024; e += 256) {
            int i = e >> 5, j = e & 31, r = ridx[e];
            sc[h * 1152 + i * 36 + j] = bf2f(Bq[i * 144 + r]) + bf2f(Bk[j * 144 + r]);
        }
        __syncthreads();
    }

    for (int pi = wv; pi < 8; pi += 4) {
        int h = pi >> 2, m = (pi >> 1) & 1, n = pi & 1;
        s16x8 a = {0, 0, 0, 0, 0, 0, 0, 0}, b = {0, 0, 0, 0, 0, 0, 0, 0};
        if (lg < 2) {
            a = *(const s16x8*)(qsb + (m * 16 + lr) * 40 + h * 16 + lg * 8);
            b = *(const s16x8*)(ksb + (n * 16 + lr) * 40 + h * 16 + lg * 8);
        }
        f32x4 acc = {0.f, 0.f, 0.f, 0.f};
        acc = __builtin_amdgcn_mfma_f32_16x16x32_bf16(a, b, acc, 0, 0, 0);
#pragma unroll
        for (int r = 0; r < 4; r++)
            sc[h * 1152 + (m * 16 + lg * 4 + r) * 36 + n * 16 + lr] += acc[r];
    }
    __syncthreads();

    {
        int rr = t >> 2, sub = t & 3;
        int h = rr >> 5, i = rr & 31, j0 = sub * 8;
        const float* srow = sc + h * 1152 + i * 36 + j0;
        float pv[8];
        float m_ = -1e30f;
#pragma unroll
        for (int jj = 0; jj < 8; jj++) { pv[jj] = srow[jj]; m_ = fmaxf(m_, pv[jj]); }
        m_ = fmaxf(m_, __shfl_xor(m_, 1));
        m_ = fmaxf(m_, __shfl_xor(m_, 2));
        float sum = 0.f;
#pragma unroll
        for (int jj = 0; jj < 8; jj++) { pv[jj] = __expf(pv[jj] - m_); sum += pv[jj]; }
        sum += __shfl_xor(sum, 1);
        sum += __shfl_xor(sum, 2);
        float inv = 1.f / sum;
        __syncthreads();
        u16* prow = psb + h * 1280 + i * 40 + j0;
#pragma unroll
        for (int jj = 0; jj < 8; jj++) prow[jj] = f2bf(pv[jj] * inv);
    }
    __syncthreads();

    for (int o = t; o < CAP * 16; o += 256) {
        int i = o >> 4, hp = o & 15, h = hp >> 3;
        const u16* prow = psb + h * 1280 + i * 40;
        const int* rrow = ridx + i * 32;
        float a0 = 0.f, a1 = 0.f;
#pragma unroll 8
        for (int j = 0; j < CAP; j++) {
            int r = rrow[j];
            float p = bf2f(prow[j]);
            u32 tv2 = *(const u32*)(tvb + r * 32 + hp * 2);
            a0 = fmaf(p, __uint_as_float(tv2 << 16), a0);
            a1 = fmaf(p, __uint_as_float(tv2 & 0xffff0000u), a1);
        }
        ot[i * 36 + hp * 2] = a0;
        ot[i * 36 + hp * 2 + 1] = a1;
    }
    __syncthreads();

    {
        int h = wv >> 1, m = wv & 1;
        s16x8 a = *(const s16x8*)(psb + h * 1280 + (m * 16 + lr) * 40 + lg * 8);
        s16x8 b = *(const s16x8*)(vsT + (h * 16 + lr) * 40 + lg * 8);
        f32x4 acc = {0.f, 0.f, 0.f, 0.f};
        acc = __builtin_amdgcn_mfma_f32_16x16x32_bf16(a, b, acc, 0, 0, 0);
#pragma unroll
        for (int r = 0; r < 4; r++)
            ot[(m * 16 + lg * 4 + r) * 36 + h * 16 + lr] += acc[r];
    }
    __syncthreads();

    {
        int m = wv >> 1, n = wv & 1;
        union { s16x8 v; u16 h[8]; } a;
        const float* orow = ot + (m * 16 + lr) * 36 + lg * 8;
#pragma unroll
        for (int e = 0; e < 8; e++) a.h[e] = f2bf(orow[e]);
        s16x8 b = *(const s16x8*)(wprojB + ((n * 64 + l) << 3));
        f32x4 acc = {0.f, 0.f, 0.f, 0.f};
        acc = __builtin_amdgcn_mfma_f32_16x16x32_bf16(a.v, b, acc, 0, 0, 0);
        int c = n * 16 + lr;
        float bb = Pf[352 + c];
#pragma unroll
        for (int r = 0; r < 4; r++) {
            int tok = m * 16 + lg * 4 + r;
            int gi = win_idx[w * 32 + tok];
            out[(long)gi * 32 + c] = x[(long)gi * 32 + c] + bb + acc[r];
        }
    }
}

// ---- ws byte offsets ----
#define B_PF     0
#define B_FLAG   1536
#define B_ACTA   2048
#define B_ACTB   4196352
#define B_FEATS  8390656
#define B_WA1    8914944
#define B_WA2    8970240
#define B_WB1    9025536
#define B_WB2    9080832
#define B_WIN    9136128
#define B_WQKVB  9144320
#define B_WPROJB 9150464
#define B_TQBF   9152512
#define B_TKBF   9170944
#define B_TVBF   9189376

extern "C" void kernel_launch(void* const* d_in, const int* in_sizes, int n_in,
                              void* d_out, int out_size, void* d_ws, size_t ws_size,
                              hipStream_t stream) {
    const void* feats  = d_in[0];
    const int* pairs   = (const int*)d_in[1];
    const int* win_idx = (const int*)d_in[2];
    const int* rel_idx = (const int*)d_in[3];

    char* wsb = (char*)d_ws;
    float* Pf = (float*)(wsb + B_PF);
    int* flag = (int*)(wsb + B_FLAG);
    u16* actA = (u16*)(wsb + B_ACTA);
    u16* actB = (u16*)(wsb + B_ACTB);
    u16* fbf  = (u16*)(wsb + B_FEATS);
    u16* WpA1 = (u16*)(wsb + B_WA1);
    u16* WpA2 = (u16*)(wsb + B_WA2);
    u16* WpB1 = (u16*)(wsb + B_WB1);
    u16* WpB2 = (u16*)(wsb + B_WB2);
    u16* WpIN = (u16*)(wsb + B_WIN);
    u16* wqkvB  = (u16*)(wsb + B_WQKVB);
    u16* wprojB = (u16*)(wsb + B_WPROJB);
    u16* tqB = (u16*)(wsb + B_TQBF);
    u16* tkB = (u16*)(wsb + B_TKBF);
    u16* tvb = (u16*)(wsb + B_TVBF);
    float* X  = (float*)d_out;

    detect_kernel<<<1, 256, 0, stream>>>((const u32*)feats, flag);

    Ptrs pp;
    for (int i = 0; i < 24; i++) pp.p[i] = d_in[i];
    prep_all<<<dim3(1024, 9), 256, 0, stream>>>(pp, flag, fbf,
                                                WpA1, WpA2, WpB1, WpB2, WpIN,
                                                wqkvB, wprojB, tqB, tkB, tvb, Pf);

    convin_mfma<<<1024, 256, 0, stream>>>(fbf, pairs, WpIN, Pf + 0, X, actA);
    conv32_lds<4><<<512, 256, 0, stream>>>(actA, pairs, WpA1, Pf + 64,  X, actB);
    conv32_lds<7><<<512, 256, 0, stream>>>(actB, pairs, WpA2, Pf + 128, X, actA);
    conv32_lds<4><<<512, 256, 0, stream>>>(actA, pairs, WpB1, Pf + 192, X, actB);
    conv32_lds<3><<<512, 256, 0, stream>>>(actB, pairs, WpB2, Pf, X, actA);

    attn5_kernel<<<NWIN, 256, 0, stream>>>(X, win_idx, rel_idx,
                                           wqkvB, wprojB, Pf,
                                           tqB, tkB, tvb, X);
}

// Round 11
// 113.402 us; speedup vs baseline: 1.4846x; 1.1211x over previous
//
#include <hip/hip_runtime.h>

typedef unsigned short u16;
typedef unsigned int u32;

#define N_PTS 65536
#define KK 27
#define CIN 4
#define CC 32
#define NWIN 2048
#define CAP 32
#define NH 2
#define HD 16

typedef short s16x8 __attribute__((ext_vector_type(8)));
typedef float f32x4 __attribute__((ext_vector_type(4)));

__device__ __forceinline__ float bf2f(u16 h) { return __uint_as_float(((u32)h) << 16); }
__device__ __forceinline__ u16 f2bf(float f) {
    u32 u = __float_as_uint(f);
    u32 r = (u + 0x7FFFu + ((u >> 16) & 1u)) >> 16;
    return (u16)r;
}
__device__ __forceinline__ float ldany(const void* src, int i, bool isbf) {
    return isbf ? bf2f(((const u16*)src)[i]) : ((const float*)src)[i];
}
__device__ __forceinline__ u16 ldbf(const void* src, int i, bool isbf) {
    return isbf ? ((const u16*)src)[i] : f2bf(((const float*)src)[i]);
}

// ---- input float-dtype detection ----
__global__ void detect_kernel(const u32* __restrict__ w, int* flag) {
    int t = threadIdx.x;
    int cnt = 0;
    for (int i = t; i < 4096; i += 256) {
        u32 e = (w[i] >> 7) & 0xFFu;
        cnt += (e >= 100 && e <= 140) ? 1 : 0;
    }
    __shared__ int red[256];
    red[t] = cnt;
    __syncthreads();
    for (int s = 128; s > 0; s >>= 1) {
        if (t < s) red[t] += red[t + s];
        __syncthreads();
    }
    if (t == 0) flag[0] = (red[0] > 2048) ? 1 : 0;
}

// ---- single prep kernel ----
struct Ptrs { const void* p[24]; };

__global__ __launch_bounds__(256) void prep_all(
    Ptrs in, const int* __restrict__ flag,
    u16* __restrict__ fbf,
    u16* __restrict__ WpA1, u16* __restrict__ WpA2,
    u16* __restrict__ WpB1, u16* __restrict__ WpB2, u16* __restrict__ WpIN,
    u16* __restrict__ wqkvB, u16* __restrict__ wprojB,
    u16* __restrict__ tqB, u16* __restrict__ tkB, u16* __restrict__ tvb,
    float* __restrict__ Pf)
{
    bool isbf = flag[0] != 0;
    int seg = blockIdx.y;
    int i = blockIdx.x * 256 + threadIdx.x;
    if (seg == 0) {
        if (i < N_PTS * CIN) fbf[i] = ldbf(in.p[0], i, isbf);
        return;
    }
    if (seg <= 4) {
        if (i < 27648) {
            int e = i & 7, l = (i >> 3) & 63, dt = (i >> 9) & 1, k = i >> 10;
            const void* src = in.p[seg == 1 ? 7 : seg == 2 ? 10 : seg == 3 ? 13 : 16];
            u16* dst = seg == 1 ? WpA1 : seg == 2 ? WpA2 : seg == 3 ? WpB1 : WpB2;
            dst[i] = ldbf(src, k * 1024 + ((l >> 4) * 8 + e) * 32 + dt * 16 + (l & 15), isbf);
        }
        return;
    }
    if (seg == 5) {
        if (i < 4096) {
            int e = i & 7, l = (i >> 3) & 63, dt = (i >> 9) & 1, kk = i >> 10;
            int g = kk * 32 + (l >> 4) * 8 + e;
            int tp = g >> 2, c = g & 3;
            WpIN[i] = (tp < KK) ? ldbf(in.p[4], tp * 128 + c * 32 + dt * 16 + (l & 15), isbf) : (u16)0;
        }
        return;
    }
    if (seg == 6) {
        if (i < 3072) {
            int e = i & 7, l = (i >> 3) & 63, n = i >> 9;
            wqkvB[i] = ldbf(in.p[17], ((l >> 4) * 8 + e) * 96 + n * 16 + (l & 15), isbf);
        } else if (i < 4096) {
            int o2 = i - 3072;
            int e = o2 & 7, l = (o2 >> 3) & 63, n = o2 >> 9;
            wprojB[o2] = ldbf(in.p[19], ((l >> 4) * 8 + e) * 32 + n * 16 + (l & 15), isbf);
        }
        return;
    }
    if (seg == 7) {
        // tq/tk in MFMA B-fragment order; tv plain [144][32]
        if (i < 9216) {
            int e = i & 7, l = (i >> 3) & 63, nn = i >> 9;
            int n = nn % 9, h = nn / 9, lr = l & 15, lg = l >> 4;
            int k = lg * 8 + e;
            tqB[i] = (k < HD) ? ldbf(in.p[21], (n * 16 + lr) * 32 + h * 16 + k, isbf) : (u16)0;
        } else if (i < 18432) {
            int o2 = i - 9216;
            int e = o2 & 7, l = (o2 >> 3) & 63, nn = o2 >> 9;
            int n = nn % 9, h = nn / 9, lr = l & 15, lg = l >> 4;
            int k = lg * 8 + e;
            tkB[o2] = (k < HD) ? ldbf(in.p[22], (n * 16 + lr) * 32 + h * 16 + k, isbf) : (u16)0;
        } else if (i < 23040) {
            int o2 = i - 18432;
            tvb[o2] = ldbf(in.p[23], o2, isbf);
        }
        return;
    }
    // seg 8: GB(8x32) | bqkv(96)@256 | bproj(32)@352
    if (i < 256) {
        const int srcs[8] = {5, 6, 8, 9, 11, 12, 14, 15};
        Pf[i] = ldany(in.p[srcs[i >> 5]], i & 31, isbf);
    } else if (i < 352) {
        Pf[i] = ldany(in.p[18], i - 256, isbf);
    } else if (i < 384) {
        Pf[i] = ldany(in.p[20], i - 352, isbf);
    }
}

// ---- MFMA input conv: batch-load phase then compute phase ----
__global__ __launch_bounds__(256) void convin_mfma(
    const u16* __restrict__ fb, const int* __restrict__ pairs,
    const u16* __restrict__ Wp, const float* __restrict__ gb,
    float* __restrict__ xbuf, u16* __restrict__ act_out)
{
    int t = threadIdx.x;
    int wv = t >> 6, l = t & 63;
    int lr = l & 15, lg = l >> 4;
    int p0 = (blockIdx.x * 4 + wv) * 16;
    int rowaddr = p0 + lr;

    int ia[4], ib[4];
    u32 ma[4], mb[4];
#pragma unroll
    for (int kk = 0; kk < 4; kk++) {
        int t0 = kk * 8 + lg * 2;
        int ta = t0 < 26 ? t0 : 26;
        int tb = (t0 + 1) < 26 ? (t0 + 1) : 26;
        ia[kk] = pairs[ta * N_PTS + rowaddr];
        ib[kk] = pairs[tb * N_PTS + rowaddr];
        ma[kk] = (t0 < KK && ia[kk] >= 0) ? 0xFFFFFFFFu : 0u;
        mb[kk] = (t0 + 1 < KK && ib[kk] >= 0) ? 0xFFFFFFFFu : 0u;
    }
    uint2 qa[4], qb[4];
    s16x8 b0[4], b1[4];
#pragma unroll
    for (int kk = 0; kk < 4; kk++) {
        qa[kk] = *(const uint2*)(fb + (long)(ia[kk] < 0 ? 0 : ia[kk]) * CIN);
        qb[kk] = *(const uint2*)(fb + (long)(ib[kk] < 0 ? 0 : ib[kk]) * CIN);
        const s16x8* wb = (const s16x8*)Wp + kk * 128 + l;
        b0[kk] = wb[0];
        b1[kk] = wb[64];
    }

    f32x4 acc0 = {0.f, 0.f, 0.f, 0.f}, acc1 = {0.f, 0.f, 0.f, 0.f};
#pragma unroll
    for (int kk = 0; kk < 4; kk++) {
        union { uint4 q; s16x8 v; } a;
        a.q = make_uint4(qa[kk].x & ma[kk], qa[kk].y & ma[kk],
                         qb[kk].x & mb[kk], qb[kk].y & mb[kk]);
        acc0 = __builtin_amdgcn_mfma_f32_16x16x32_bf16(a.v, b0[kk], acc0, 0, 0, 0);
        acc1 = __builtin_amdgcn_mfma_f32_16x16x32_bf16(a.v, b1[kk], acc1, 0, 0, 0);
    }
    float g0 = gb[lr], b0v = gb[32 + lr], g1 = gb[16 + lr], b1v = gb[48 + lr];
#pragma unroll
    for (int r = 0; r < 4; r++) {
        int row = p0 + lg * 4 + r;
        long o0 = (long)row * 32 + lr, o1 = o0 + 16;
        float v0 = acc0[r], v1 = acc1[r];
        xbuf[o0] = v0; xbuf[o1] = v1;
        act_out[o0] = f2bf(fmaxf(fmaf(v0, g0, b0v), 0.f));
        act_out[o1] = f2bf(fmaxf(fmaf(v1, g1, b1v), 0.f));
    }
}

// ---- MFMA 32->32 gather conv; LDS weights + 512-thread blocks ----
// 8 waves/block x 2 tiles, grid 256; 55KB LDS -> 2 blocks/CU = 4 waves/SIMD.
// M: bit0 READ_X, bit1 WRITE_X, bit2 WRITE_ACT
template <int M>
__global__ __launch_bounds__(512, 4) void conv32_lds(
    const u16* __restrict__ act_in, const int* __restrict__ pairs,
    const u16* __restrict__ Wp, const float* __restrict__ gb,
    float* __restrict__ xbuf, u16* __restrict__ act_out)
{
    __shared__ u16 wlds[KK * 1024];   // 55296 B
    int t = threadIdx.x;
    int wv = t >> 6, l = t & 63;
    int lr = l & 15, lg = l >> 4;

    // cooperative coalesced stage: 3456 uint4
    {
        const uint4* src = (const uint4*)Wp;
        uint4* dst = (uint4*)wlds;
#pragma unroll
        for (int q = 0; q < 7; q++) {
            int e = q * 512 + t;
            if (e < 3456) dst[e] = src[e];
        }
    }
    __syncthreads();

    float g0 = 0.f, b0v = 0.f, g1 = 0.f, b1v = 0.f;
    if (M & 4) { g0 = gb[lr]; b0v = gb[32 + lr]; g1 = gb[16 + lr]; b1v = gb[48 + lr]; }

#pragma unroll
    for (int tile = 0; tile < 2; tile++) {
        int p0 = ((blockIdx.x * 8 + wv) * 2 + tile) * 16;
        int rowaddr = p0 + lr;

        int idx[KK];
#pragma unroll
        for (int k = 0; k < KK; k++) idx[k] = pairs[k * N_PTS + rowaddr];

        uint4 qr[8];
#pragma unroll
        for (int k = 0; k < 8; k++) {
            int ic = idx[k] < 0 ? 0 : idx[k];
            qr[k] = *(const uint4*)(act_in + (long)ic * CC + lg * 8);
        }

        f32x4 acc0 = {0.f, 0.f, 0.f, 0.f}, acc1 = {0.f, 0.f, 0.f, 0.f};
#pragma unroll
        for (int k = 0; k < KK; k++) {
            int s = k & 7;
            uint4 q = qr[s];
            if (k + 8 < KK) {
                int kn = k + 8;
                int ic = idx[kn] < 0 ? 0 : idx[kn];
                qr[s] = *(const uint4*)(act_in + (long)ic * CC + lg * 8);
            }
            u32 msk = idx[k] >= 0 ? 0xFFFFFFFFu : 0u;
            q.x &= msk; q.y &= msk; q.z &= msk; q.w &= msk;
            union { uint4 q; s16x8 v; } a;
            a.q = q;
            const s16x8* wb = (const s16x8*)wlds + k * 128 + l;
            s16x8 w0 = wb[0];
            s16x8 w1 = wb[64];
            acc0 = __builtin_amdgcn_mfma_f32_16x16x32_bf16(a.v, w0, acc0, 0, 0, 0);
            acc1 = __builtin_amdgcn_mfma_f32_16x16x32_bf16(a.v, w1, acc1, 0, 0, 0);
        }
#pragma unroll
        for (int r = 0; r < 4; r++) {
            int row = p0 + lg * 4 + r;
            long o0 = (long)row * 32 + lr, o1 = o0 + 16;
            float v0 = acc0[r], v1 = acc1[r];
            if (M & 1) { v0 += xbuf[o0]; v1 += xbuf[o1]; }
            if (M & 2) { xbuf[o0] = v0; xbuf[o1] = v1; }
            if (M & 4) {
                act_out[o0] = f2bf(fmaxf(fmaf(v0, g0, b0v), 0.f));
                act_out[o1] = f2bf(fmaxf(fmaf(v1, g1, b1v), 0.f));
            }
        }
    }
}

// ---- attention v6: 2 windows per 512-thread block (occupancy x1.5) ----
#define A5_RIDX 0
#define A5_QSB  4096
#define A5_KSB  6656
#define A5_VST  9216
#define A5_SC   11776
#define A5_BQ   20992
#define A5_BK   30208
#define A5_SIZE 39424

__global__ __launch_bounds__(512) void attn6_kernel(
    const float* __restrict__ x, const int* __restrict__ win_idx,
    const int* __restrict__ rel_idx,
    const u16* __restrict__ wqkvB, const u16* __restrict__ wprojB,
    const float* __restrict__ Pf,
    const u16* __restrict__ tqB, const u16* __restrict__ tkB, const u16* __restrict__ tvb,
    float* __restrict__ out)
{
    __shared__ __align__(16) char arena2[2][A5_SIZE];
    int t = threadIdx.x;
    int wl = t >> 8;            // window half within block
    int tl = t & 255;
    int w = blockIdx.x * 2 + wl;
    char* arena = arena2[wl];

    int*   ridx = (int*)(arena + A5_RIDX);
    u16*   qsb  = (u16*)(arena + A5_QSB);
    u16*   ksb  = (u16*)(arena + A5_KSB);
    u16*   vsT  = (u16*)(arena + A5_VST);
    float* sc   = (float*)(arena + A5_SC);
    u16*   psb  = (u16*)(arena + A5_SC);
    u16*   Bq   = (u16*)(arena + A5_BQ);
    u16*   Bk   = (u16*)(arena + A5_BK);
    float* ot   = (float*)(arena + A5_BQ);

    int wv = tl >> 6, l = tl & 63, lr = l & 15, lg = l >> 4;

    {
        int4 r4 = *(const int4*)(rel_idx + (long)w * 1024 + tl * 4);
        *(int4*)(ridx + tl * 4) = r4;
    }
    {
        const float* bqkv = Pf + 256;
        for (int pi = wv; pi < 12; pi += 4) {
            int n = pi >> 1, m = pi & 1;
            int gi = win_idx[w * 32 + m * 16 + lr];
            const float* xr = x + (long)gi * 32 + lg * 8;
            float4 x0 = *(const float4*)(xr);
            float4 x1 = *(const float4*)(xr + 4);
            union { s16x8 v; u16 h[8]; } a;
            a.h[0] = f2bf(x0.x); a.h[1] = f2bf(x0.y); a.h[2] = f2bf(x0.z); a.h[3] = f2bf(x0.w);
            a.h[4] = f2bf(x1.x); a.h[5] = f2bf(x1.y); a.h[6] = f2bf(x1.z); a.h[7] = f2bf(x1.w);
            s16x8 b = *(const s16x8*)(wqkvB + ((n * 64 + l) << 3));
            f32x4 acc = {0.f, 0.f, 0.f, 0.f};
            acc = __builtin_amdgcn_mfma_f32_16x16x32_bf16(a.v, b, acc, 0, 0, 0);
            int tt = n * 16 + lr;
            float bias = bqkv[tt];
#pragma unroll
            for (int r = 0; r < 4; r++) {
                int tok = m * 16 + lg * 4 + r;
                float v = acc[r] + bias;
                if (tt < 32)      qsb[tok * 40 + tt] = f2bf(v * 0.25f);
                else if (tt < 64) ksb[tok * 40 + (tt - 32)] = f2bf(v);
                else              vsT[(tt - 64) * 40 + tok] = f2bf(v);
            }
        }
    }
    __syncthreads();

    // per-h rel-bias: wave-role mapping (no int div), hoisted A-fragment
    for (int h = 0; h < NH; h++) {
        {
            int tb = wv >> 1, m = wv & 1;
            const u16* src = tb ? ksb : qsb;
            const u16* tab = tb ? tkB : tqB;
            u16* dst = tb ? Bk : Bq;
            s16x8 a = {0, 0, 0, 0, 0, 0, 0, 0};
            if (lg < 2) a = *(const s16x8*)(src + (m * 16 + lr) * 40 + h * 16 + lg * 8);
#pragma unroll
            for (int n = 0; n < 9; n++) {
                s16x8 b = *(const s16x8*)(tab + (((h * 9 + n) * 64 + l) << 3));
                f32x4 acc = {0.f, 0.f, 0.f, 0.f};
                acc = __builtin_amdgcn_mfma_f32_16x16x32_bf16(a, b, acc, 0, 0, 0);
#pragma unroll
                for (int r = 0; r < 4; r++)
                    dst[(m * 16 + lg * 4 + r) * 144 + n * 16 + lr] = f2bf(acc[r]);
            }
        }
        __syncthreads();
        for (int e = tl; e < 1024; e += 256) {
            int i = e >> 5, j = e & 31, r = ridx[e];
            sc[h * 1152 + i * 36 + j] = bf2f(Bq[i * 144 + r]) + bf2f(Bk[j * 144 + r]);
        }
        __syncthreads();
    }

    for (int pi = wv; pi < 8; pi += 4) {
        int h = pi >> 2, m = (pi >> 1) & 1, n = pi & 1;
        s16x8 a = {0, 0, 0, 0, 0, 0, 0, 0}, b = {0, 0, 0, 0, 0, 0, 0, 0};
        if (lg < 2) {
            a = *(const s16x8*)(qsb + (m * 16 + lr) * 40 + h * 16 + lg * 8);
            b = *(const s16x8*)(ksb + (n * 16 + lr) * 40 + h * 16 + lg * 8);
        }
        f32x4 acc = {0.f, 0.f, 0.f, 0.f};
        acc = __builtin_amdgcn_mfma_f32_16x16x32_bf16(a, b, acc, 0, 0, 0);
#pragma unroll
        for (int r = 0; r < 4; r++)
            sc[h * 1152 + (m * 16 + lg * 4 + r) * 36 + n * 16 + lr] += acc[r];
    }
    __syncthreads();

    {
        int rr = tl >> 2, sub = tl & 3;
        int h = rr >> 5, i = rr & 31, j0 = sub * 8;
        const float* srow = sc + h * 1152 + i * 36 + j0;
        float pv[8];
        float m_ = -1e30f;
#pragma unroll
        for (int jj = 0; jj < 8; jj++) { pv[jj] = srow[jj]; m_ = fmaxf(m_, pv[jj]); }
        m_ = fmaxf(m_, __shfl_xor(m_, 1));
        m_ = fmaxf(m_, __shfl_xor(m_, 2));
        float sum = 0.f;
#pragma unroll
        for (int jj = 0; jj < 8; jj++) { pv[jj] = __expf(pv[jj] - m_); sum += pv[jj]; }
        sum += __shfl_xor(sum, 1);
        sum += __shfl_xor(sum, 2);
        float inv = 1.f / sum;
        __syncthreads();
        u16* prow = psb + h * 1280 + i * 40 + j0;
#pragma unroll
        for (int jj = 0; jj < 8; jj++) prow[jj] = f2bf(pv[jj] * inv);
    }
    __syncthreads();

    for (int o = tl; o < CAP * 16; o += 256) {
        int i = o >> 4, hp = o & 15, h = hp >> 3;
        const u16* prow = psb + h * 1280 + i * 40;
        const int* rrow = ridx + i * 32;
        float a0 = 0.f, a1 = 0.f;
#pragma unroll 8
        for (int j = 0; j < CAP; j++) {
            int r = rrow[j];
            float p = bf2f(prow[j]);
            u32 tv2 = *(const u32*)(tvb + r * 32 + hp * 2);
            a0 = fmaf(p, __uint_as_float(tv2 << 16), a0);
            a1 = fmaf(p, __uint_as_float(tv2 & 0xffff0000u), a1);
        }
        ot[i * 36 + hp * 2] = a0;
        ot[i * 36 + hp * 2 + 1] = a1;
    }
    __syncthreads();

    {
        int h = wv >> 1, m = wv & 1;
        s16x8 a = *(const s16x8*)(psb + h * 1280 + (m * 16 + lr) * 40 + lg * 8);
        s16x8 b = *(const s16x8*)(vsT + (h * 16 + lr) * 40 + lg * 8);
        f32x4 acc = {0.f, 0.f, 0.f, 0.f};
        acc = __builtin_amdgcn_mfma_f32_16x16x32_bf16(a, b, acc, 0, 0, 0);
#pragma unroll
        for (int r = 0; r < 4; r++)
            ot[(m * 16 + lg * 4 + r) * 36 + h * 16 + lr] += acc[r];
    }
    __syncthreads();

    {
        int m = wv >> 1, n = wv & 1;
        union { s16x8 v; u16 h[8]; } a;
        const float* orow = ot + (m * 16 + lr) * 36 + lg * 8;
#pragma unroll
        for (int e = 0; e < 8; e++) a.h[e] = f2bf(orow[e]);
        s16x8 b = *(const s16x8*)(wprojB + ((n * 64 + l) << 3));
        f32x4 acc = {0.f, 0.f, 0.f, 0.f};
        acc = __builtin_amdgcn_mfma_f32_16x16x32_bf16(a.v, b, acc, 0, 0, 0);
        int c = n * 16 + lr;
        float bb = Pf[352 + c];
#pragma unroll
        for (int r = 0; r < 4; r++) {
            int tok = m * 16 + lg * 4 + r;
            int gi = win_idx[w * 32 + tok];
            out[(long)gi * 32 + c] = x[(long)gi * 32 + c] + bb + acc[r];
        }
    }
}

// ---- ws byte offsets ----
#define B_PF     0
#define B_FLAG   1536
#define B_ACTA   2048
#define B_ACTB   4196352
#define B_FEATS  8390656
#define B_WA1    8914944
#define B_WA2    8970240
#define B_WB1    9025536
#define B_WB2    9080832
#define B_WIN    9136128
#define B_WQKVB  9144320
#define B_WPROJB 9150464
#define B_TQBF   9152512
#define B_TKBF   9170944
#define B_TVBF   9189376

extern "C" void kernel_launch(void* const* d_in, const int* in_sizes, int n_in,
                              void* d_out, int out_size, void* d_ws, size_t ws_size,
                              hipStream_t stream) {
    const void* feats  = d_in[0];
    const int* pairs   = (const int*)d_in[1];
    const int* win_idx = (const int*)d_in[2];
    const int* rel_idx = (const int*)d_in[3];

    char* wsb = (char*)d_ws;
    float* Pf = (float*)(wsb + B_PF);
    int* flag = (int*)(wsb + B_FLAG);
    u16* actA = (u16*)(wsb + B_ACTA);
    u16* actB = (u16*)(wsb + B_ACTB);
    u16* fbf  = (u16*)(wsb + B_FEATS);
    u16* WpA1 = (u16*)(wsb + B_WA1);
    u16* WpA2 = (u16*)(wsb + B_WA2);
    u16* WpB1 = (u16*)(wsb + B_WB1);
    u16* WpB2 = (u16*)(wsb + B_WB2);
    u16* WpIN = (u16*)(wsb + B_WIN);
    u16* wqkvB  = (u16*)(wsb + B_WQKVB);
    u16* wprojB = (u16*)(wsb + B_WPROJB);
    u16* tqB = (u16*)(wsb + B_TQBF);
    u16* tkB = (u16*)(wsb + B_TKBF);
    u16* tvb = (u16*)(wsb + B_TVBF);
    float* X  = (float*)d_out;

    detect_kernel<<<1, 256, 0, stream>>>((const u32*)feats, flag);

    Ptrs pp;
    for (int i = 0; i < 24; i++) pp.p[i] = d_in[i];
    prep_all<<<dim3(1024, 9), 256, 0, stream>>>(pp, flag, fbf,
                                                WpA1, WpA2, WpB1, WpB2, WpIN,
                                                wqkvB, wprojB, tqB, tkB, tvb, Pf);

    convin_mfma<<<1024, 256, 0, stream>>>(fbf, pairs, WpIN, Pf + 0, X, actA);
    conv32_lds<4><<<256, 512, 0, stream>>>(actA, pairs, WpA1, Pf + 64,  X, actB);
    conv32_lds<7><<<256, 512, 0, stream>>>(actB, pairs, WpA2, Pf + 128, X, actA);
    conv32_lds<4><<<256, 512, 0, stream>>>(actA, pairs, WpB1, Pf + 192, X, actB);
    conv32_lds<3><<<256, 512, 0, stream>>>(actB, pairs, WpB2, Pf, X, actA);

    attn6_kernel<<<NWIN / 2, 512, 0, stream>>>(X, win_idx, rel_idx,
                                               wqkvB, wprojB, Pf,
                                               tqB, tkB, tvb, X);
}